// Round 5
// baseline (1495.325 us; speedup 1.0000x reference)
//
#include <hip/hip_runtime.h>

#define N_NODES 50000
#define N_EDGES 800000
#define DIM 256
#define NG 64
#define EPS_BN 1e-5f

typedef _Float16 f16;
typedef _Float16 half8 __attribute__((ext_vector_type(8)));
typedef _Float16 half4 __attribute__((ext_vector_type(4)));
typedef float floatx4 __attribute__((ext_vector_type(4)));

// ============================ input BN statistics (fp32 x) ============================
__global__ __launch_bounds__(256) void col_stats_kernel(const float* __restrict__ X, int n,
                                                        float* __restrict__ sums) {
    int c = threadIdx.x;
    float s = 0.f, q = 0.f;
    for (int i = blockIdx.x; i < n; i += gridDim.x) {
        float v = X[(size_t)i * DIM + c];
        s += v; q += v * v;
    }
    atomicAdd(&sums[c], s);
    atomicAdd(&sums[DIM + c], q);
}

__global__ void finalize_stats_kernel(const float* __restrict__ sums, float* __restrict__ mr, float inv_n) {
    int c = threadIdx.x;
    float m = sums[c] * inv_n;
    float v = sums[DIM + c] * inv_n - m * m;
    mr[c] = m;
    mr[DIM + c] = rsqrtf(v + EPS_BN);
}

// input BN apply: fp32 x -> fp16 Af
__global__ __launch_bounds__(256) void bn_apply_in_kernel(const float* __restrict__ Xin, f16* __restrict__ Af,
                                                          const float* __restrict__ mr, const float* __restrict__ g,
                                                          const float* __restrict__ b, int n) {
    int c = threadIdx.x;
    float mean = mr[c], rstd = mr[DIM + c], gg = g[c], bb = b[c];
    for (int i = blockIdx.x; i < n; i += gridDim.x) {
        size_t idx = (size_t)i * DIM + c;
        float v = Xin[idx];
        v = (v - mean) * rstd * gg + bb;
        Af[idx] = (f16)v;
    }
}

// layer BN apply: fp16 C (pre-relu) -> relu -> BN -> (+residual Af) -> fp16 Af
__global__ __launch_bounds__(256) void bn_apply_kernel(const f16* __restrict__ Cin, f16* __restrict__ Af,
                                                       const float* __restrict__ mr, const float* __restrict__ g,
                                                       const float* __restrict__ b, int n, int residual) {
    int c = threadIdx.x;
    float mean = mr[c], rstd = mr[DIM + c], gg = g[c], bb = b[c];
    for (int i = blockIdx.x; i < n; i += gridDim.x) {
        size_t idx = (size_t)i * DIM + c;
        float v = (float)Cin[idx];
        v = fmaxf(v, 0.f);
        v = (v - mean) * rstd * gg + bb;
        if (residual) v += (float)Af[idx];
        Af[idx] = (f16)v;
    }
}

// ============================ weight conversion: Wt[m][k] = (f16)W[k][m] ============================
__global__ void convert_wT_kernel(const float* __restrict__ W, f16* __restrict__ Wt, int K, int M) {
    int idx = blockIdx.x * 256 + threadIdx.x;
    if (idx < K * M) {
        int m = idx / K, k = idx % K;
        Wt[idx] = (f16)W[(size_t)k * M + m];
    }
}

// ============================ degree / CSR build ============================
__global__ void count_int_kernel(const int* __restrict__ idx, int n, int* __restrict__ cnt) {
    for (int i = blockIdx.x * blockDim.x + threadIdx.x; i < n; i += gridDim.x * blockDim.x)
        atomicAdd(&cnt[idx[i]], 1);
}

#define SCHUNK 2048
__global__ __launch_bounds__(256) void scan1_kernel(const int* __restrict__ cnt, int n,
                                                    int* __restrict__ outp, int* __restrict__ bsums,
                                                    float* __restrict__ dinv) {
    __shared__ int lds[256];
    int t = threadIdx.x;
    int base = blockIdx.x * SCHUNK + t * 8;
    int v[8]; int s = 0;
#pragma unroll
    for (int j = 0; j < 8; j++) {
        int id = base + j;
        int x = 0;
        if (id < n) { x = cnt[id]; dinv[id] = rsqrtf((float)x + 1.0f); }
        v[j] = s; s += x;
    }
    lds[t] = s; __syncthreads();
    for (int o = 1; o < 256; o <<= 1) {
        int add = (t >= o) ? lds[t - o] : 0;
        __syncthreads();
        lds[t] += add;
        __syncthreads();
    }
    int excl = lds[t] - s;
#pragma unroll
    for (int j = 0; j < 8; j++) { int id = base + j; if (id < n) outp[id] = excl + v[j]; }
    if (t == 255) bsums[blockIdx.x] = lds[255];
}

__global__ void scan2_kernel(int* bsums, int nb) {
    if (threadIdx.x == 0 && blockIdx.x == 0) {
        int r = 0;
        for (int i = 0; i < nb; i++) { int t = bsums[i]; bsums[i] = r; r += t; }
    }
}

__global__ void scan3_kernel(int* __restrict__ outp, const int* __restrict__ bsums, int n, int total) {
    int i = blockIdx.x * blockDim.x + threadIdx.x;
    if (i < n) outp[i] += bsums[i / SCHUNK];
    if (i == 0) outp[n] = total;
}

__global__ void scatter_kernel(const int* __restrict__ src, const int* __restrict__ dst, int ne,
                               const int* __restrict__ rowp, int* __restrict__ fill, int* __restrict__ ss) {
    for (int e = blockIdx.x * blockDim.x + threadIdx.x; e < ne; e += gridDim.x * blockDim.x) {
        int d = dst[e];
        int pos = rowp[d] + atomicAdd(&fill[d], 1);
        ss[pos] = src[e];
    }
}

// ============================ graph ranges (batch sorted -> no atomics) ============================
__global__ void graph_bounds_kernel(const int* __restrict__ batch, int n, int* __restrict__ start) {
    int i = blockIdx.x * blockDim.x + threadIdx.x;
    if (i < n) {
        int b = batch[i];
        if (i == 0 || batch[i - 1] != b) start[b] = i;
    }
}

__global__ void graph_offsets2_kernel(const int* __restrict__ start, int* __restrict__ off, int* __restrict__ cnt) {
    if (threadIdx.x == 0 && blockIdx.x == 0) {
        int nxt = N_NODES;
        for (int g = NG - 1; g >= 0; --g) {
            int s = start[g];
            int o = (s < 0) ? nxt : s;
            off[g] = o;
            cnt[g] = nxt - o;
            nxt = o;
        }
    }
}

// ============================ GCN edge aggregation (fp16 gather, fp32 accum) ============================
// writes C (fp16, pre-relu) AND accumulates BN stats of relu(C) into `stats` (fused col_stats)
__global__ __launch_bounds__(256) void gcn_agg_kernel(const f16* __restrict__ h, const int* __restrict__ rowp,
                                                      const int* __restrict__ ss, const float* __restrict__ dinv,
                                                      const float* __restrict__ bias, f16* __restrict__ out,
                                                      float* __restrict__ stats, int n) {
    int wave = threadIdx.x >> 6;
    int lane = threadIdx.x & 63;
    int c = lane * 4;
    float4 bv = *(const float4*)&bias[c];
    float s0 = 0.f, s1 = 0.f, s2 = 0.f, s3 = 0.f;
    float q0 = 0.f, q1 = 0.f, q2 = 0.f, q3 = 0.f;
    for (int row = blockIdx.x * 4 + wave; row < n; row += gridDim.x * 4) {
        float ax = 0.f, ay = 0.f, az = 0.f, aw = 0.f;
        int e0 = rowp[row], e1 = rowp[row + 1];
        int e = e0;
        for (; e + 3 < e1; e += 4) {
            int i0 = ss[e], i1 = ss[e + 1], i2 = ss[e + 2], i3 = ss[e + 3];
            float w0 = dinv[i0], w1 = dinv[i1], w2 = dinv[i2], w3 = dinv[i3];
            half4 h0 = *(const half4*)&h[(size_t)i0 * DIM + c];
            half4 h1 = *(const half4*)&h[(size_t)i1 * DIM + c];
            half4 h2 = *(const half4*)&h[(size_t)i2 * DIM + c];
            half4 h3 = *(const half4*)&h[(size_t)i3 * DIM + c];
            ax += w0 * (float)h0[0] + w1 * (float)h1[0] + w2 * (float)h2[0] + w3 * (float)h3[0];
            ay += w0 * (float)h0[1] + w1 * (float)h1[1] + w2 * (float)h2[1] + w3 * (float)h3[1];
            az += w0 * (float)h0[2] + w1 * (float)h1[2] + w2 * (float)h2[2] + w3 * (float)h3[2];
            aw += w0 * (float)h0[3] + w1 * (float)h1[3] + w2 * (float)h2[3] + w3 * (float)h3[3];
        }
        for (; e < e1; e++) {
            int si = ss[e];
            float ww = dinv[si];
            half4 hv = *(const half4*)&h[(size_t)si * DIM + c];
            ax += ww * (float)hv[0]; ay += ww * (float)hv[1];
            az += ww * (float)hv[2]; aw += ww * (float)hv[3];
        }
        float di = dinv[row];
        float d2 = di * di;
        half4 hs = *(const half4*)&h[(size_t)row * DIM + c];
        float rx = di * ax + d2 * (float)hs[0] + bv.x;
        float ry = di * ay + d2 * (float)hs[1] + bv.y;
        float rz = di * az + d2 * (float)hs[2] + bv.z;
        float rw = di * aw + d2 * (float)hs[3] + bv.w;
        half4 o; o[0] = (f16)rx; o[1] = (f16)ry; o[2] = (f16)rz; o[3] = (f16)rw;
        *(half4*)&out[(size_t)row * DIM + c] = o;
        float t;
        t = fmaxf(rx, 0.f); s0 += t; q0 += t * t;
        t = fmaxf(ry, 0.f); s1 += t; q1 += t * t;
        t = fmaxf(rz, 0.f); s2 += t; q2 += t * t;
        t = fmaxf(rw, 0.f); s3 += t; q3 += t * t;
    }
    // block-level stats reduction: 4 waves -> one atomic set per block
    __shared__ float sred[4][64][4];
    __shared__ float qred[4][64][4];
    sred[wave][lane][0] = s0; sred[wave][lane][1] = s1; sred[wave][lane][2] = s2; sred[wave][lane][3] = s3;
    qred[wave][lane][0] = q0; qred[wave][lane][1] = q1; qred[wave][lane][2] = q2; qred[wave][lane][3] = q3;
    __syncthreads();
    if (wave == 0) {
        float a0 = 0.f, a1 = 0.f, a2 = 0.f, a3 = 0.f, b0 = 0.f, b1 = 0.f, b2 = 0.f, b3 = 0.f;
#pragma unroll
        for (int ww = 0; ww < 4; ww++) {
            a0 += sred[ww][lane][0]; a1 += sred[ww][lane][1]; a2 += sred[ww][lane][2]; a3 += sred[ww][lane][3];
            b0 += qred[ww][lane][0]; b1 += qred[ww][lane][1]; b2 += qred[ww][lane][2]; b3 += qred[ww][lane][3];
        }
        atomicAdd(&stats[c + 0], a0); atomicAdd(&stats[c + 1], a1);
        atomicAdd(&stats[c + 2], a2); atomicAdd(&stats[c + 3], a3);
        atomicAdd(&stats[DIM + c + 0], b0); atomicAdd(&stats[DIM + c + 1], b1);
        atomicAdd(&stats[DIM + c + 2], b2); atomicAdd(&stats[DIM + c + 3], b3);
    }
}

// ============================ fp16 MFMA GEMM: C[n,M] (f16) = Af[n,K] @ Wt^T ============================
#define BM 128
#define BN 128
#define BK 32
#define LDP 40
__global__ __launch_bounds__(256) void gemm_f16_kernel(const f16* __restrict__ Af, const f16* __restrict__ Wt,
                                                       f16* __restrict__ C, int n, int K, int M) {
    __shared__ __align__(16) f16 As[BM * LDP];
    __shared__ __align__(16) f16 Bs[BN * LDP];
    int tid = threadIdx.x;
    int wave = tid >> 6, lane = tid & 63;
    int wm = wave >> 1, wn = wave & 1;
    int q = lane >> 4, l16 = lane & 15;
    int bm = blockIdx.x * BM, bn = blockIdx.y * BN;
    floatx4 acc[4][4] = {};
    for (int k0 = 0; k0 < K; k0 += BK) {
#pragma unroll
        for (int rr = 0; rr < 2; rr++) {
            int cidx = tid + rr * 256;
            int row = cidx >> 2, off = (cidx & 3) * 8;
            int arow = bm + row; if (arow >= n) arow = n - 1;
            *(float4*)&As[row * LDP + off] = *(const float4*)&Af[(size_t)arow * K + k0 + off];
            int brow = bn + row;
            *(float4*)&Bs[row * LDP + off] = *(const float4*)&Wt[(size_t)brow * K + k0 + off];
        }
        __syncthreads();
        half8 af[4], bf[4];
#pragma unroll
        for (int i = 0; i < 4; i++) af[i] = *(half8*)&As[(wm * 64 + i * 16 + l16) * LDP + q * 8];
#pragma unroll
        for (int j = 0; j < 4; j++) bf[j] = *(half8*)&Bs[(wn * 64 + j * 16 + l16) * LDP + q * 8];
#pragma unroll
        for (int i = 0; i < 4; i++)
#pragma unroll
            for (int j = 0; j < 4; j++)
                acc[i][j] = __builtin_amdgcn_mfma_f32_16x16x32_f16(af[i], bf[j], acc[i][j], 0, 0, 0);
        __syncthreads();
    }
#pragma unroll
    for (int i = 0; i < 4; i++)
#pragma unroll
        for (int j = 0; j < 4; j++) {
            int col = bn + wn * 64 + j * 16 + l16;
#pragma unroll
            for (int r = 0; r < 4; r++) {
                int row = bm + wm * 64 + i * 16 + q * 4 + r;
                if (row < n) C[(size_t)row * M + col] = (f16)acc[i][j][r];
            }
        }
}

// ============ attention GEMM (M=128) with fused leaky-relu + Wa2 dot -> score ============
__global__ __launch_bounds__(256) void gemm_attn_kernel(const f16* __restrict__ Af, const f16* __restrict__ Wt,
                                                        const float* __restrict__ ba1, const float* __restrict__ Wa2,
                                                        const float* __restrict__ ba2, float* __restrict__ score,
                                                        int n, int K) {
    __shared__ __align__(16) f16 As[BM * LDP];
    __shared__ __align__(16) f16 Bs[128 * LDP];
    __shared__ float scred[128][2];
    int tid = threadIdx.x;
    int wave = tid >> 6, lane = tid & 63;
    int wm = wave >> 1, wn = wave & 1;
    int q = lane >> 4, l16 = lane & 15;
    int bm = blockIdx.x * BM;
    floatx4 acc[4][4] = {};
    for (int k0 = 0; k0 < K; k0 += BK) {
#pragma unroll
        for (int rr = 0; rr < 2; rr++) {
            int cidx = tid + rr * 256;
            int row = cidx >> 2, off = (cidx & 3) * 8;
            int arow = bm + row; if (arow >= n) arow = n - 1;
            *(float4*)&As[row * LDP + off] = *(const float4*)&Af[(size_t)arow * K + k0 + off];
            *(float4*)&Bs[row * LDP + off] = *(const float4*)&Wt[(size_t)row * K + k0 + off];
        }
        __syncthreads();
        half8 af[4], bf[4];
#pragma unroll
        for (int i = 0; i < 4; i++) af[i] = *(half8*)&As[(wm * 64 + i * 16 + l16) * LDP + q * 8];
#pragma unroll
        for (int j = 0; j < 4; j++) bf[j] = *(half8*)&Bs[(wn * 64 + j * 16 + l16) * LDP + q * 8];
#pragma unroll
        for (int i = 0; i < 4; i++)
#pragma unroll
            for (int j = 0; j < 4; j++)
                acc[i][j] = __builtin_amdgcn_mfma_f32_16x16x32_f16(af[i], bf[j], acc[i][j], 0, 0, 0);
        __syncthreads();
    }
    float ba1v[4], wa2v[4];
#pragma unroll
    for (int j = 0; j < 4; j++) {
        int col = wn * 64 + j * 16 + l16;
        ba1v[j] = ba1[col];
        wa2v[j] = Wa2[col];
    }
#pragma unroll
    for (int i = 0; i < 4; i++)
#pragma unroll
        for (int r = 0; r < 4; r++) {
            float p = 0.f;
#pragma unroll
            for (int j = 0; j < 4; j++) {
                float v = acc[i][j][r] + ba1v[j];
                v = (v > 0.f) ? v : 0.01f * v;
                p += v * wa2v[j];
            }
#pragma unroll
            for (int o = 1; o < 16; o <<= 1) p += __shfl_xor(p, o);
            if (l16 == 0) scred[wm * 64 + i * 16 + q * 4 + r][wn] = p;
        }
    __syncthreads();
    if (tid < 128) {
        int grow = bm + tid;
        if (grow < n) score[grow] = scred[tid][0] + scred[tid][1] + ba2[0];
    }
}

// ============================ softmax reductions ============================
__global__ __launch_bounds__(256) void reduce_max_kernel(const float* __restrict__ s, int n, float* __restrict__ part) {
    __shared__ float lds[256];
    float m = -3.0e38f;
    for (int i = blockIdx.x * 256 + threadIdx.x; i < n; i += gridDim.x * 256) m = fmaxf(m, s[i]);
    lds[threadIdx.x] = m; __syncthreads();
    for (int o = 128; o > 0; o >>= 1) {
        if (threadIdx.x < o) lds[threadIdx.x] = fmaxf(lds[threadIdx.x], lds[threadIdx.x + o]);
        __syncthreads();
    }
    if (threadIdx.x == 0) part[blockIdx.x] = lds[0];
}

// each block re-reduces the 256 partial maxes inline, then computes its partial sum-exp
__global__ __launch_bounds__(256) void reduce_sumexp_kernel(const float* __restrict__ s, int n,
                                                            const float* __restrict__ part_max,
                                                            float* __restrict__ part_sum) {
    __shared__ float lds[256];
    int t = threadIdx.x;
    lds[t] = part_max[t]; __syncthreads();
    for (int o = 128; o > 0; o >>= 1) {
        if (t < o) lds[t] = fmaxf(lds[t], lds[t + o]);
        __syncthreads();
    }
    float mx = lds[0];
    __syncthreads();
    float acc = 0.f;
    for (int i = blockIdx.x * 256 + t; i < n; i += gridDim.x * 256) acc += expf(s[i] - mx);
    lds[t] = acc; __syncthreads();
    for (int o = 128; o > 0; o >>= 1) {
        if (t < o) lds[t] += lds[t + o];
        __syncthreads();
    }
    if (t == 0) part_sum[blockIdx.x] = lds[0];
}

// pooled[g,c] += striped sum of Af[i,c]*exp(score[i]-mx); grid (NG, 8)
__global__ __launch_bounds__(256) void pool_kernel(const f16* __restrict__ Af, const float* __restrict__ score,
                                                   const int* __restrict__ offs, const int* __restrict__ cnts,
                                                   const float* __restrict__ part_max, float* __restrict__ pooled) {
    __shared__ float lds[256];
    int c = threadIdx.x;
    lds[c] = part_max[c]; __syncthreads();
    for (int o = 128; o > 0; o >>= 1) {
        if (c < o) lds[c] = fmaxf(lds[c], lds[c + o]);
        __syncthreads();
    }
    float mx = lds[0];
    int g = blockIdx.x;
    int st = offs[g], cn = cnts[g];
    float acc = 0.f;
    for (int i = (int)blockIdx.y; i < cn; i += 32) {
        int i1 = i + 8, i2 = i + 16, i3 = i + 24;
        float s0 = score[st + i];
        float s1 = (i1 < cn) ? score[st + i1] : -3.0e38f;
        float s2 = (i2 < cn) ? score[st + i2] : -3.0e38f;
        float s3 = (i3 < cn) ? score[st + i3] : -3.0e38f;
        float a0 = (float)Af[(size_t)(st + i) * DIM + c];
        float a1 = (i1 < cn) ? (float)Af[(size_t)(st + i1) * DIM + c] : 0.f;
        float a2 = (i2 < cn) ? (float)Af[(size_t)(st + i2) * DIM + c] : 0.f;
        float a3 = (i3 < cn) ? (float)Af[(size_t)(st + i3) * DIM + c] : 0.f;
        acc += a0 * expf(s0 - mx) + a1 * expf(s1 - mx) + a2 * expf(s2 - mx) + a3 * expf(s3 - mx);
    }
    atomicAdd(&pooled[g * DIM + c], acc);
}

__global__ __launch_bounds__(256) void out_kernel(const float* __restrict__ pooled, const int* __restrict__ cnt,
                                                  const float* __restrict__ part_sum, const float* __restrict__ Wo,
                                                  const float* __restrict__ bo, float* __restrict__ out) {
    __shared__ float l0[256], l1[256];
    int g = blockIdx.x, c = threadIdx.x;
    l0[c] = part_sum[c]; __syncthreads();
    for (int o = 128; o > 0; o >>= 1) {
        if (c < o) l0[c] += l0[c + o];
        __syncthreads();
    }
    float denom = l0[0];
    __syncthreads();
    float scale = 1.f / (denom * fmaxf((float)cnt[g], 1.f));
    float v = pooled[g * DIM + c] * scale;
    l0[c] = v * Wo[c * 2];
    l1[c] = v * Wo[c * 2 + 1];
    __syncthreads();
    for (int o = 128; o > 0; o >>= 1) {
        if (c < o) { l0[c] += l0[c + o]; l1[c] += l1[c + o]; }
        __syncthreads();
    }
    if (c == 0) { out[g * 2] = l0[0] + bo[0]; out[g * 2 + 1] = l1[0] + bo[1]; }
}

// ============================ launch ============================
extern "C" void kernel_launch(void* const* d_in, const int* in_sizes, int n_in,
                              void* d_out, int out_size, void* d_ws, size_t ws_size,
                              hipStream_t stream) {
    const float* x       = (const float*)d_in[0];
    const int*   ei      = (const int*)d_in[1];
    const int*   batch   = (const int*)d_in[2];
    const float* bn_in_g = (const float*)d_in[3];
    const float* bn_in_b = (const float*)d_in[4];
    const float* Ws[3]   = {(const float*)d_in[5],  (const float*)d_in[9],  (const float*)d_in[13]};
    const float* bs[3]   = {(const float*)d_in[6],  (const float*)d_in[10], (const float*)d_in[14]};
    const float* gs[3]   = {(const float*)d_in[7],  (const float*)d_in[11], (const float*)d_in[15]};
    const float* bbs[3]  = {(const float*)d_in[8],  (const float*)d_in[12], (const float*)d_in[16]};
    const float* Wa1 = (const float*)d_in[17];
    const float* ba1 = (const float*)d_in[18];
    const float* Wa2 = (const float*)d_in[19];
    const float* ba2 = (const float*)d_in[20];
    const float* Wo  = (const float*)d_in[21];
    const float* bo  = (const float*)d_in[22];

    char* w = (char*)d_ws;
    size_t off = 0;
    auto alloc = [&](size_t bytes) -> void* {
        void* p = w + off;
        off += (bytes + 255) & ~(size_t)255;
        return p;
    };
    // --- zeroed region (single memset): deg, fill, stats(4x512), pooled ---
    int*   deg     = (int*)alloc((size_t)N_NODES * 4);
    int*   fill    = (int*)alloc((size_t)N_NODES * 4);
    float* statsA  = (float*)alloc(4 * 512 * 4);          // [0]=input, [1..3]=layers
    float* pooled  = (float*)alloc((size_t)NG * DIM * 4);
    size_t zero_span = off;
    // --- rest ---
    f16*   Afh  = (f16*)alloc((size_t)N_NODES * DIM * 2);   // features fp16
    f16*   Bh   = (f16*)alloc((size_t)N_NODES * DIM * 2);   // h = xp @ W (fp16, gather input)
    f16*   Ch   = (f16*)alloc((size_t)N_NODES * DIM * 2);   // aggregated pre-BN (fp16)
    f16*   Wt[3];
    for (int l = 0; l < 3; l++) Wt[l] = (f16*)alloc((size_t)DIM * DIM * 2);
    f16*   Wa1t = (f16*)alloc((size_t)128 * DIM * 2);
    int* sorted_src = (int*)alloc((size_t)N_EDGES * 4);
    float* dinv = (float*)alloc((size_t)N_NODES * 4);
    int* rowp   = (int*)alloc((size_t)(N_NODES + 1) * 4);
    float* score = (float*)alloc((size_t)N_NODES * 4);
    float* mr    = (float*)alloc(512 * 4);
    int* bsums   = (int*)alloc(64 * 4);
    float* part_max = (float*)alloc(256 * 4);
    float* part_sum = (float*)alloc(256 * 4);
    int* gstart  = (int*)alloc(64 * 4);
    int* cnt_g   = (int*)alloc(64 * 4);
    int* off_g   = (int*)alloc(64 * 4);

    const int* src = ei;
    const int* dst = ei + N_EDGES;
    const int NSCAN = (N_NODES + SCHUNK - 1) / SCHUNK;

    hipMemsetAsync(d_ws, 0, zero_span, stream);
    hipMemsetAsync(gstart, 0xff, 64 * 4, stream);

    // ---- degree + CSR (dst-sorted edges); dinv fused into scan1 ----
    count_int_kernel<<<3125, 256, 0, stream>>>(dst, N_EDGES, deg);
    scan1_kernel<<<NSCAN, 256, 0, stream>>>(deg, N_NODES, rowp, bsums, dinv);
    scan2_kernel<<<1, 64, 0, stream>>>(bsums, NSCAN);
    scan3_kernel<<<(N_NODES + 255) / 256, 256, 0, stream>>>(rowp, bsums, N_NODES, N_EDGES);
    scatter_kernel<<<3125, 256, 0, stream>>>(src, dst, N_EDGES, rowp, fill, sorted_src);

    // ---- graph ranges from sorted batch ----
    graph_bounds_kernel<<<(N_NODES + 255) / 256, 256, 0, stream>>>(batch, N_NODES, gstart);
    graph_offsets2_kernel<<<1, 64, 0, stream>>>(gstart, off_g, cnt_g);

    // ---- weight conversion (fp32 -> fp16, transposed) ----
    for (int l = 0; l < 3; l++)
        convert_wT_kernel<<<DIM * DIM / 256, 256, 0, stream>>>(Ws[l], Wt[l], DIM, DIM);
    convert_wT_kernel<<<128 * DIM / 256, 256, 0, stream>>>(Wa1, Wa1t, DIM, 128);

    // ---- input BN ----
    col_stats_kernel<<<512, 256, 0, stream>>>(x, N_NODES, statsA);
    finalize_stats_kernel<<<1, 256, 0, stream>>>(statsA, mr, 1.f / N_NODES);
    bn_apply_in_kernel<<<1024, 256, 0, stream>>>(x, Afh, mr, bn_in_g, bn_in_b, N_NODES);

    // ---- GCN layers (stats fused into gcn_agg epilogue) ----
    dim3 ggrid((N_NODES + BM - 1) / BM, DIM / BN);
    for (int l = 0; l < 3; l++) {
        float* statsL = statsA + 512 * (l + 1);
        gemm_f16_kernel<<<ggrid, 256, 0, stream>>>(Afh, Wt[l], Bh, N_NODES, DIM, DIM);
        gcn_agg_kernel<<<3125, 256, 0, stream>>>(Bh, rowp, sorted_src, dinv, bs[l], Ch, statsL, N_NODES);
        finalize_stats_kernel<<<1, 256, 0, stream>>>(statsL, mr, 1.f / N_NODES);
        bn_apply_kernel<<<1024, 256, 0, stream>>>(Ch, Afh, mr, gs[l], bbs[l], N_NODES, (l > 0) ? 1 : 0);
    }

    // ---- attention scores (fused GEMM epilogue) ----
    gemm_attn_kernel<<<(N_NODES + BM - 1) / BM, 256, 0, stream>>>(Afh, Wa1t, ba1, Wa2, ba2, score, N_NODES, DIM);
    reduce_max_kernel<<<256, 256, 0, stream>>>(score, N_NODES, part_max);
    reduce_sumexp_kernel<<<256, 256, 0, stream>>>(score, N_NODES, part_max, part_sum);

    // ---- per-graph pooling ----
    pool_kernel<<<dim3(NG, 8), 256, 0, stream>>>(Afh, score, off_g, cnt_g, part_max, pooled);
    out_kernel<<<NG, 256, 0, stream>>>(pooled, cnt_g, part_sum, Wo, bo, (float*)d_out);
}

// Round 6
// 787.084 us; speedup vs baseline: 1.8998x; 1.8998x over previous
//
#include <hip/hip_runtime.h>

#define N_NODES 50000
#define N_EDGES 800000
#define DIM 256
#define NG 64
#define EPS_BN 1e-5f
#define NB_AGG 3125   // gcn_agg grid (partial-stats stride)
#define NB_COL 512    // input col_stats grid

typedef _Float16 f16;
typedef _Float16 half8 __attribute__((ext_vector_type(8)));
typedef _Float16 half4 __attribute__((ext_vector_type(4)));
typedef float floatx4 __attribute__((ext_vector_type(4)));

// ============================ input BN statistics (fp32 x) -> per-block partials ============================
// part[c*NB_COL + b] = block b's partial sum of column c;  part[(256+c)*NB_COL + b] = partial sumsq
__global__ __launch_bounds__(256) void col_stats_kernel(const float* __restrict__ X, int n,
                                                        float* __restrict__ part) {
    int c = threadIdx.x;
    float s = 0.f, q = 0.f;
    for (int i = blockIdx.x; i < n; i += gridDim.x) {
        float v = X[(size_t)i * DIM + c];
        s += v; q += v * v;
    }
    part[(size_t)c * NB_COL + blockIdx.x] = s;
    part[(size_t)(DIM + c) * NB_COL + blockIdx.x] = q;
}

// wave-per-column reduction of partials: stats[c] = sum_i part[c*nrows + i]   (512 columns)
__global__ __launch_bounds__(256) void reduce_stats_kernel(const float* __restrict__ part, int nrows,
                                                           float* __restrict__ stats) {
    int wave = threadIdx.x >> 6, lane = threadIdx.x & 63;
    int c = blockIdx.x * 4 + wave;           // 0..511
    float t = 0.f;
    for (int i = lane; i < nrows; i += 64) t += part[(size_t)c * nrows + i];
    for (int o = 32; o > 0; o >>= 1) t += __shfl_down(t, o);
    if (lane == 0) stats[c] = t;
}

__global__ void finalize_stats_kernel(const float* __restrict__ sums, float* __restrict__ mr, float inv_n) {
    int c = threadIdx.x;
    float m = sums[c] * inv_n;
    float v = sums[DIM + c] * inv_n - m * m;
    mr[c] = m;
    mr[DIM + c] = rsqrtf(v + EPS_BN);
}

// input BN apply: fp32 x -> fp16 Af
__global__ __launch_bounds__(256) void bn_apply_in_kernel(const float* __restrict__ Xin, f16* __restrict__ Af,
                                                          const float* __restrict__ mr, const float* __restrict__ g,
                                                          const float* __restrict__ b, int n) {
    int c = threadIdx.x;
    float mean = mr[c], rstd = mr[DIM + c], gg = g[c], bb = b[c];
    for (int i = blockIdx.x; i < n; i += gridDim.x) {
        size_t idx = (size_t)i * DIM + c;
        float v = Xin[idx];
        v = (v - mean) * rstd * gg + bb;
        Af[idx] = (f16)v;
    }
}

// layer BN apply: fp16 C (pre-relu) -> relu -> BN -> (+residual Af) -> fp16 Af
__global__ __launch_bounds__(256) void bn_apply_kernel(const f16* __restrict__ Cin, f16* __restrict__ Af,
                                                       const float* __restrict__ mr, const float* __restrict__ g,
                                                       const float* __restrict__ b, int n, int residual) {
    int c = threadIdx.x;
    float mean = mr[c], rstd = mr[DIM + c], gg = g[c], bb = b[c];
    for (int i = blockIdx.x; i < n; i += gridDim.x) {
        size_t idx = (size_t)i * DIM + c;
        float v = (float)Cin[idx];
        v = fmaxf(v, 0.f);
        v = (v - mean) * rstd * gg + bb;
        if (residual) v += (float)Af[idx];
        Af[idx] = (f16)v;
    }
}

// ============================ weight conversion: Wt[m][k] = (f16)W[k][m] ============================
__global__ void convert_wT_kernel(const float* __restrict__ W, f16* __restrict__ Wt, int K, int M) {
    int idx = blockIdx.x * 256 + threadIdx.x;
    if (idx < K * M) {
        int m = idx / K, k = idx % K;
        Wt[idx] = (f16)W[(size_t)k * M + m];
    }
}

// ============================ degree / CSR build ============================
__global__ void count_int_kernel(const int* __restrict__ idx, int n, int* __restrict__ cnt) {
    for (int i = blockIdx.x * blockDim.x + threadIdx.x; i < n; i += gridDim.x * blockDim.x)
        atomicAdd(&cnt[idx[i]], 1);
}

#define SCHUNK 2048
__global__ __launch_bounds__(256) void scan1_kernel(const int* __restrict__ cnt, int n,
                                                    int* __restrict__ outp, int* __restrict__ bsums,
                                                    float* __restrict__ dinv) {
    __shared__ int lds[256];
    int t = threadIdx.x;
    int base = blockIdx.x * SCHUNK + t * 8;
    int v[8]; int s = 0;
#pragma unroll
    for (int j = 0; j < 8; j++) {
        int id = base + j;
        int x = 0;
        if (id < n) { x = cnt[id]; dinv[id] = rsqrtf((float)x + 1.0f); }
        v[j] = s; s += x;
    }
    lds[t] = s; __syncthreads();
    for (int o = 1; o < 256; o <<= 1) {
        int add = (t >= o) ? lds[t - o] : 0;
        __syncthreads();
        lds[t] += add;
        __syncthreads();
    }
    int excl = lds[t] - s;
#pragma unroll
    for (int j = 0; j < 8; j++) { int id = base + j; if (id < n) outp[id] = excl + v[j]; }
    if (t == 255) bsums[blockIdx.x] = lds[255];
}

__global__ void scan2_kernel(int* bsums, int nb) {
    if (threadIdx.x == 0 && blockIdx.x == 0) {
        int r = 0;
        for (int i = 0; i < nb; i++) { int t = bsums[i]; bsums[i] = r; r += t; }
    }
}

__global__ void scan3_kernel(int* __restrict__ outp, const int* __restrict__ bsums, int n, int total) {
    int i = blockIdx.x * blockDim.x + threadIdx.x;
    if (i < n) outp[i] += bsums[i / SCHUNK];
    if (i == 0) outp[n] = total;
}

__global__ void scatter_kernel(const int* __restrict__ src, const int* __restrict__ dst, int ne,
                               const int* __restrict__ rowp, int* __restrict__ fill, int* __restrict__ ss) {
    for (int e = blockIdx.x * blockDim.x + threadIdx.x; e < ne; e += gridDim.x * blockDim.x) {
        int d = dst[e];
        int pos = rowp[d] + atomicAdd(&fill[d], 1);
        ss[pos] = src[e];
    }
}

// ============================ graph ranges (batch sorted -> no atomics) ============================
__global__ void graph_bounds_kernel(const int* __restrict__ batch, int n, int* __restrict__ start) {
    int i = blockIdx.x * blockDim.x + threadIdx.x;
    if (i < n) {
        int b = batch[i];
        if (i == 0 || batch[i - 1] != b) start[b] = i;
    }
}

__global__ void graph_offsets2_kernel(const int* __restrict__ start, int* __restrict__ off, int* __restrict__ cnt) {
    if (threadIdx.x == 0 && blockIdx.x == 0) {
        int nxt = N_NODES;
        for (int g = NG - 1; g >= 0; --g) {
            int s = start[g];
            int o = (s < 0) ? nxt : s;
            off[g] = o;
            cnt[g] = nxt - o;
            nxt = o;
        }
    }
}

// ============================ GCN edge aggregation (fp16 gather, fp32 accum) ============================
// writes C (fp16, pre-relu) AND per-block BN-stat partials of relu(C) (no atomics)
__global__ __launch_bounds__(256) void gcn_agg_kernel(const f16* __restrict__ h, const int* __restrict__ rowp,
                                                      const int* __restrict__ ss, const float* __restrict__ dinv,
                                                      const float* __restrict__ bias, f16* __restrict__ out,
                                                      float* __restrict__ part, int n) {
    int wave = threadIdx.x >> 6;
    int lane = threadIdx.x & 63;
    int c = lane * 4;
    float4 bv = *(const float4*)&bias[c];
    float s0 = 0.f, s1 = 0.f, s2 = 0.f, s3 = 0.f;
    float q0 = 0.f, q1 = 0.f, q2 = 0.f, q3 = 0.f;
    for (int row = blockIdx.x * 4 + wave; row < n; row += gridDim.x * 4) {
        float ax = 0.f, ay = 0.f, az = 0.f, aw = 0.f;
        int e0 = rowp[row], e1 = rowp[row + 1];
        int e = e0;
        for (; e + 3 < e1; e += 4) {
            int i0 = ss[e], i1 = ss[e + 1], i2 = ss[e + 2], i3 = ss[e + 3];
            float w0 = dinv[i0], w1 = dinv[i1], w2 = dinv[i2], w3 = dinv[i3];
            half4 h0 = *(const half4*)&h[(size_t)i0 * DIM + c];
            half4 h1 = *(const half4*)&h[(size_t)i1 * DIM + c];
            half4 h2 = *(const half4*)&h[(size_t)i2 * DIM + c];
            half4 h3 = *(const half4*)&h[(size_t)i3 * DIM + c];
            ax += w0 * (float)h0[0] + w1 * (float)h1[0] + w2 * (float)h2[0] + w3 * (float)h3[0];
            ay += w0 * (float)h0[1] + w1 * (float)h1[1] + w2 * (float)h2[1] + w3 * (float)h3[1];
            az += w0 * (float)h0[2] + w1 * (float)h1[2] + w2 * (float)h2[2] + w3 * (float)h3[2];
            aw += w0 * (float)h0[3] + w1 * (float)h1[3] + w2 * (float)h2[3] + w3 * (float)h3[3];
        }
        for (; e < e1; e++) {
            int si = ss[e];
            float ww = dinv[si];
            half4 hv = *(const half4*)&h[(size_t)si * DIM + c];
            ax += ww * (float)hv[0]; ay += ww * (float)hv[1];
            az += ww * (float)hv[2]; aw += ww * (float)hv[3];
        }
        float di = dinv[row];
        float d2 = di * di;
        half4 hs = *(const half4*)&h[(size_t)row * DIM + c];
        float rx = di * ax + d2 * (float)hs[0] + bv.x;
        float ry = di * ay + d2 * (float)hs[1] + bv.y;
        float rz = di * az + d2 * (float)hs[2] + bv.z;
        float rw = di * aw + d2 * (float)hs[3] + bv.w;
        half4 o; o[0] = (f16)rx; o[1] = (f16)ry; o[2] = (f16)rz; o[3] = (f16)rw;
        *(half4*)&out[(size_t)row * DIM + c] = o;
        float t;
        t = fmaxf(rx, 0.f); s0 += t; q0 += t * t;
        t = fmaxf(ry, 0.f); s1 += t; q1 += t * t;
        t = fmaxf(rz, 0.f); s2 += t; q2 += t * t;
        t = fmaxf(rw, 0.f); s3 += t; q3 += t * t;
    }
    // cross-wave LDS reduction, then plain (non-atomic) per-block partial store
    __shared__ float sred[4][64][4];
    __shared__ float qred[4][64][4];
    sred[wave][lane][0] = s0; sred[wave][lane][1] = s1; sred[wave][lane][2] = s2; sred[wave][lane][3] = s3;
    qred[wave][lane][0] = q0; qred[wave][lane][1] = q1; qred[wave][lane][2] = q2; qred[wave][lane][3] = q3;
    __syncthreads();
    if (wave == 0) {
        int b = blockIdx.x;
#pragma unroll
        for (int j = 0; j < 4; j++) {
            float a = 0.f, qq = 0.f;
#pragma unroll
            for (int ww = 0; ww < 4; ww++) { a += sred[ww][lane][j]; qq += qred[ww][lane][j]; }
            part[(size_t)(c + j) * NB_AGG + b] = a;
            part[(size_t)(DIM + c + j) * NB_AGG + b] = qq;
        }
    }
}

// ============================ fp16 MFMA GEMM: C[n,M] (f16) = Af[n,K] @ Wt^T ============================
#define BM 128
#define BN 128
#define BK 32
#define LDP 40
__global__ __launch_bounds__(256) void gemm_f16_kernel(const f16* __restrict__ Af, const f16* __restrict__ Wt,
                                                       f16* __restrict__ C, int n, int K, int M) {
    __shared__ __align__(16) f16 As[BM * LDP];
    __shared__ __align__(16) f16 Bs[BN * LDP];
    int tid = threadIdx.x;
    int wave = tid >> 6, lane = tid & 63;
    int wm = wave >> 1, wn = wave & 1;
    int q = lane >> 4, l16 = lane & 15;
    int bm = blockIdx.x * BM, bn = blockIdx.y * BN;
    floatx4 acc[4][4] = {};
    for (int k0 = 0; k0 < K; k0 += BK) {
#pragma unroll
        for (int rr = 0; rr < 2; rr++) {
            int cidx = tid + rr * 256;
            int row = cidx >> 2, off = (cidx & 3) * 8;
            int arow = bm + row; if (arow >= n) arow = n - 1;
            *(float4*)&As[row * LDP + off] = *(const float4*)&Af[(size_t)arow * K + k0 + off];
            int brow = bn + row;
            *(float4*)&Bs[row * LDP + off] = *(const float4*)&Wt[(size_t)brow * K + k0 + off];
        }
        __syncthreads();
        half8 af[4], bf[4];
#pragma unroll
        for (int i = 0; i < 4; i++) af[i] = *(half8*)&As[(wm * 64 + i * 16 + l16) * LDP + q * 8];
#pragma unroll
        for (int j = 0; j < 4; j++) bf[j] = *(half8*)&Bs[(wn * 64 + j * 16 + l16) * LDP + q * 8];
#pragma unroll
        for (int i = 0; i < 4; i++)
#pragma unroll
            for (int j = 0; j < 4; j++)
                acc[i][j] = __builtin_amdgcn_mfma_f32_16x16x32_f16(af[i], bf[j], acc[i][j], 0, 0, 0);
        __syncthreads();
    }
#pragma unroll
    for (int i = 0; i < 4; i++)
#pragma unroll
        for (int j = 0; j < 4; j++) {
            int col = bn + wn * 64 + j * 16 + l16;
#pragma unroll
            for (int r = 0; r < 4; r++) {
                int row = bm + wm * 64 + i * 16 + q * 4 + r;
                if (row < n) C[(size_t)row * M + col] = (f16)acc[i][j][r];
            }
        }
}

// ============ attention GEMM (M=128) with fused leaky-relu + Wa2 dot -> score ============
__global__ __launch_bounds__(256) void gemm_attn_kernel(const f16* __restrict__ Af, const f16* __restrict__ Wt,
                                                        const float* __restrict__ ba1, const float* __restrict__ Wa2,
                                                        const float* __restrict__ ba2, float* __restrict__ score,
                                                        int n, int K) {
    __shared__ __align__(16) f16 As[BM * LDP];
    __shared__ __align__(16) f16 Bs[128 * LDP];
    __shared__ float scred[128][2];
    int tid = threadIdx.x;
    int wave = tid >> 6, lane = tid & 63;
    int wm = wave >> 1, wn = wave & 1;
    int q = lane >> 4, l16 = lane & 15;
    int bm = blockIdx.x * BM;
    floatx4 acc[4][4] = {};
    for (int k0 = 0; k0 < K; k0 += BK) {
#pragma unroll
        for (int rr = 0; rr < 2; rr++) {
            int cidx = tid + rr * 256;
            int row = cidx >> 2, off = (cidx & 3) * 8;
            int arow = bm + row; if (arow >= n) arow = n - 1;
            *(float4*)&As[row * LDP + off] = *(const float4*)&Af[(size_t)arow * K + k0 + off];
            *(float4*)&Bs[row * LDP + off] = *(const float4*)&Wt[(size_t)row * K + k0 + off];
        }
        __syncthreads();
        half8 af[4], bf[4];
#pragma unroll
        for (int i = 0; i < 4; i++) af[i] = *(half8*)&As[(wm * 64 + i * 16 + l16) * LDP + q * 8];
#pragma unroll
        for (int j = 0; j < 4; j++) bf[j] = *(half8*)&Bs[(wn * 64 + j * 16 + l16) * LDP + q * 8];
#pragma unroll
        for (int i = 0; i < 4; i++)
#pragma unroll
            for (int j = 0; j < 4; j++)
                acc[i][j] = __builtin_amdgcn_mfma_f32_16x16x32_f16(af[i], bf[j], acc[i][j], 0, 0, 0);
        __syncthreads();
    }
    float ba1v[4], wa2v[4];
#pragma unroll
    for (int j = 0; j < 4; j++) {
        int col = wn * 64 + j * 16 + l16;
        ba1v[j] = ba1[col];
        wa2v[j] = Wa2[col];
    }
#pragma unroll
    for (int i = 0; i < 4; i++)
#pragma unroll
        for (int r = 0; r < 4; r++) {
            float p = 0.f;
#pragma unroll
            for (int j = 0; j < 4; j++) {
                float v = acc[i][j][r] + ba1v[j];
                v = (v > 0.f) ? v : 0.01f * v;
                p += v * wa2v[j];
            }
#pragma unroll
            for (int o = 1; o < 16; o <<= 1) p += __shfl_xor(p, o);
            if (l16 == 0) scred[wm * 64 + i * 16 + q * 4 + r][wn] = p;
        }
    __syncthreads();
    if (tid < 128) {
        int grow = bm + tid;
        if (grow < n) score[grow] = scred[tid][0] + scred[tid][1] + ba2[0];
    }
}

// ============================ softmax reductions ============================
__global__ __launch_bounds__(256) void reduce_max_kernel(const float* __restrict__ s, int n, float* __restrict__ part) {
    __shared__ float lds[256];
    float m = -3.0e38f;
    for (int i = blockIdx.x * 256 + threadIdx.x; i < n; i += gridDim.x * 256) m = fmaxf(m, s[i]);
    lds[threadIdx.x] = m; __syncthreads();
    for (int o = 128; o > 0; o >>= 1) {
        if (threadIdx.x < o) lds[threadIdx.x] = fmaxf(lds[threadIdx.x], lds[threadIdx.x + o]);
        __syncthreads();
    }
    if (threadIdx.x == 0) part[blockIdx.x] = lds[0];
}

__global__ __launch_bounds__(256) void reduce_sumexp_kernel(const float* __restrict__ s, int n,
                                                            const float* __restrict__ part_max,
                                                            float* __restrict__ part_sum) {
    __shared__ float lds[256];
    int t = threadIdx.x;
    lds[t] = part_max[t]; __syncthreads();
    for (int o = 128; o > 0; o >>= 1) {
        if (t < o) lds[t] = fmaxf(lds[t], lds[t + o]);
        __syncthreads();
    }
    float mx = lds[0];
    __syncthreads();
    float acc = 0.f;
    for (int i = blockIdx.x * 256 + t; i < n; i += gridDim.x * 256) acc += expf(s[i] - mx);
    lds[t] = acc; __syncthreads();
    for (int o = 128; o > 0; o >>= 1) {
        if (t < o) lds[t] += lds[t + o];
        __syncthreads();
    }
    if (t == 0) part_sum[blockIdx.x] = lds[0];
}

// pooled[g,c] += striped sum of Af[i,c]*exp(score[i]-mx); grid (NG, 8)
__global__ __launch_bounds__(256) void pool_kernel(const f16* __restrict__ Af, const float* __restrict__ score,
                                                   const int* __restrict__ offs, const int* __restrict__ cnts,
                                                   const float* __restrict__ part_max, float* __restrict__ pooled) {
    __shared__ float lds[256];
    int c = threadIdx.x;
    lds[c] = part_max[c]; __syncthreads();
    for (int o = 128; o > 0; o >>= 1) {
        if (c < o) lds[c] = fmaxf(lds[c], lds[c + o]);
        __syncthreads();
    }
    float mx = lds[0];
    int g = blockIdx.x;
    int st = offs[g], cn = cnts[g];
    float acc = 0.f;
    for (int i = (int)blockIdx.y; i < cn; i += 32) {
        int i1 = i + 8, i2 = i + 16, i3 = i + 24;
        float s0 = score[st + i];
        float s1 = (i1 < cn) ? score[st + i1] : -3.0e38f;
        float s2 = (i2 < cn) ? score[st + i2] : -3.0e38f;
        float s3 = (i3 < cn) ? score[st + i3] : -3.0e38f;
        float a0 = (float)Af[(size_t)(st + i) * DIM + c];
        float a1 = (i1 < cn) ? (float)Af[(size_t)(st + i1) * DIM + c] : 0.f;
        float a2 = (i2 < cn) ? (float)Af[(size_t)(st + i2) * DIM + c] : 0.f;
        float a3 = (i3 < cn) ? (float)Af[(size_t)(st + i3) * DIM + c] : 0.f;
        acc += a0 * expf(s0 - mx) + a1 * expf(s1 - mx) + a2 * expf(s2 - mx) + a3 * expf(s3 - mx);
    }
    atomicAdd(&pooled[g * DIM + c], acc);
}

__global__ __launch_bounds__(256) void out_kernel(const float* __restrict__ pooled, const int* __restrict__ cnt,
                                                  const float* __restrict__ part_sum, const float* __restrict__ Wo,
                                                  const float* __restrict__ bo, float* __restrict__ out) {
    __shared__ float l0[256], l1[256];
    int g = blockIdx.x, c = threadIdx.x;
    l0[c] = part_sum[c]; __syncthreads();
    for (int o = 128; o > 0; o >>= 1) {
        if (c < o) l0[c] += l0[c + o];
        __syncthreads();
    }
    float denom = l0[0];
    __syncthreads();
    float scale = 1.f / (denom * fmaxf((float)cnt[g], 1.f));
    float v = pooled[g * DIM + c] * scale;
    l0[c] = v * Wo[c * 2];
    l1[c] = v * Wo[c * 2 + 1];
    __syncthreads();
    for (int o = 128; o > 0; o >>= 1) {
        if (c < o) { l0[c] += l0[c + o]; l1[c] += l1[c + o]; }
        __syncthreads();
    }
    if (c == 0) { out[g * 2] = l0[0] + bo[0]; out[g * 2 + 1] = l1[0] + bo[1]; }
}

// ============================ launch ============================
extern "C" void kernel_launch(void* const* d_in, const int* in_sizes, int n_in,
                              void* d_out, int out_size, void* d_ws, size_t ws_size,
                              hipStream_t stream) {
    const float* x       = (const float*)d_in[0];
    const int*   ei      = (const int*)d_in[1];
    const int*   batch   = (const int*)d_in[2];
    const float* bn_in_g = (const float*)d_in[3];
    const float* bn_in_b = (const float*)d_in[4];
    const float* Ws[3]   = {(const float*)d_in[5],  (const float*)d_in[9],  (const float*)d_in[13]};
    const float* bs[3]   = {(const float*)d_in[6],  (const float*)d_in[10], (const float*)d_in[14]};
    const float* gs[3]   = {(const float*)d_in[7],  (const float*)d_in[11], (const float*)d_in[15]};
    const float* bbs[3]  = {(const float*)d_in[8],  (const float*)d_in[12], (const float*)d_in[16]};
    const float* Wa1 = (const float*)d_in[17];
    const float* ba1 = (const float*)d_in[18];
    const float* Wa2 = (const float*)d_in[19];
    const float* ba2 = (const float*)d_in[20];
    const float* Wo  = (const float*)d_in[21];
    const float* bo  = (const float*)d_in[22];

    char* w = (char*)d_ws;
    size_t off = 0;
    auto alloc = [&](size_t bytes) -> void* {
        void* p = w + off;
        off += (bytes + 255) & ~(size_t)255;
        return p;
    };
    // --- zeroed region (single memset): deg, fill, pooled ---
    int*   deg     = (int*)alloc((size_t)N_NODES * 4);
    int*   fill    = (int*)alloc((size_t)N_NODES * 4);
    float* pooled  = (float*)alloc((size_t)NG * DIM * 4);
    size_t zero_span = off;
    // --- rest (no zeroing needed) ---
    float* stats_part = (float*)alloc((size_t)512 * NB_AGG * 4);  // partial BN stats (transposed)
    float* statsS  = (float*)alloc(512 * 4);                      // reduced sums/sumsq
    f16*   Afh  = (f16*)alloc((size_t)N_NODES * DIM * 2);   // features fp16
    f16*   Bh   = (f16*)alloc((size_t)N_NODES * DIM * 2);   // h = xp @ W (fp16, gather input)
    f16*   Ch   = (f16*)alloc((size_t)N_NODES * DIM * 2);   // aggregated pre-BN (fp16)
    f16*   Wt[3];
    for (int l = 0; l < 3; l++) Wt[l] = (f16*)alloc((size_t)DIM * DIM * 2);
    f16*   Wa1t = (f16*)alloc((size_t)128 * DIM * 2);
    int* sorted_src = (int*)alloc((size_t)N_EDGES * 4);
    float* dinv = (float*)alloc((size_t)N_NODES * 4);
    int* rowp   = (int*)alloc((size_t)(N_NODES + 1) * 4);
    float* score = (float*)alloc((size_t)N_NODES * 4);
    float* mr    = (float*)alloc(512 * 4);
    int* bsums   = (int*)alloc(64 * 4);
    float* part_max = (float*)alloc(256 * 4);
    float* part_sum = (float*)alloc(256 * 4);
    int* gstart  = (int*)alloc(64 * 4);
    int* cnt_g   = (int*)alloc(64 * 4);
    int* off_g   = (int*)alloc(64 * 4);

    const int* src = ei;
    const int* dst = ei + N_EDGES;
    const int NSCAN = (N_NODES + SCHUNK - 1) / SCHUNK;

    hipMemsetAsync(d_ws, 0, zero_span, stream);
    hipMemsetAsync(gstart, 0xff, 64 * 4, stream);

    // ---- degree + CSR (dst-sorted edges); dinv fused into scan1 ----
    count_int_kernel<<<3125, 256, 0, stream>>>(dst, N_EDGES, deg);
    scan1_kernel<<<NSCAN, 256, 0, stream>>>(deg, N_NODES, rowp, bsums, dinv);
    scan2_kernel<<<1, 64, 0, stream>>>(bsums, NSCAN);
    scan3_kernel<<<(N_NODES + 255) / 256, 256, 0, stream>>>(rowp, bsums, N_NODES, N_EDGES);
    scatter_kernel<<<3125, 256, 0, stream>>>(src, dst, N_EDGES, rowp, fill, sorted_src);

    // ---- graph ranges from sorted batch ----
    graph_bounds_kernel<<<(N_NODES + 255) / 256, 256, 0, stream>>>(batch, N_NODES, gstart);
    graph_offsets2_kernel<<<1, 64, 0, stream>>>(gstart, off_g, cnt_g);

    // ---- weight conversion (fp32 -> fp16, transposed) ----
    for (int l = 0; l < 3; l++)
        convert_wT_kernel<<<DIM * DIM / 256, 256, 0, stream>>>(Ws[l], Wt[l], DIM, DIM);
    convert_wT_kernel<<<128 * DIM / 256, 256, 0, stream>>>(Wa1, Wa1t, DIM, 128);

    // ---- input BN (partials -> reduce -> finalize; no atomics) ----
    col_stats_kernel<<<NB_COL, 256, 0, stream>>>(x, N_NODES, stats_part);
    reduce_stats_kernel<<<128, 256, 0, stream>>>(stats_part, NB_COL, statsS);
    finalize_stats_kernel<<<1, 256, 0, stream>>>(statsS, mr, 1.f / N_NODES);
    bn_apply_in_kernel<<<1024, 256, 0, stream>>>(x, Afh, mr, bn_in_g, bn_in_b, N_NODES);

    // ---- GCN layers (stats fused into gcn_agg epilogue, atomic-free) ----
    dim3 ggrid((N_NODES + BM - 1) / BM, DIM / BN);
    for (int l = 0; l < 3; l++) {
        gemm_f16_kernel<<<ggrid, 256, 0, stream>>>(Afh, Wt[l], Bh, N_NODES, DIM, DIM);
        gcn_agg_kernel<<<NB_AGG, 256, 0, stream>>>(Bh, rowp, sorted_src, dinv, bs[l], Ch, stats_part, N_NODES);
        reduce_stats_kernel<<<128, 256, 0, stream>>>(stats_part, NB_AGG, statsS);
        finalize_stats_kernel<<<1, 256, 0, stream>>>(statsS, mr, 1.f / N_NODES);
        bn_apply_kernel<<<1024, 256, 0, stream>>>(Ch, Afh, mr, gs[l], bbs[l], N_NODES, (l > 0) ? 1 : 0);
    }

    // ---- attention scores (fused GEMM epilogue) ----
    gemm_attn_kernel<<<(N_NODES + BM - 1) / BM, 256, 0, stream>>>(Afh, Wa1t, ba1, Wa2, ba2, score, N_NODES, DIM);
    reduce_max_kernel<<<256, 256, 0, stream>>>(score, N_NODES, part_max);
    reduce_sumexp_kernel<<<256, 256, 0, stream>>>(score, N_NODES, part_max, part_sum);

    // ---- per-graph pooling ----
    pool_kernel<<<dim3(NG, 8), 256, 0, stream>>>(Afh, score, off_g, cnt_g, part_max, pooled);
    out_kernel<<<NG, 256, 0, stream>>>(pooled, cnt_g, part_sum, Wo, bo, (float*)d_out);
}

// Round 7
// 764.968 us; speedup vs baseline: 1.9548x; 1.0289x over previous
//
#include <hip/hip_runtime.h>

#define N_NODES 50000
#define N_EDGES 800000
#define DIM 256
#define NG 64
#define EPS_BN 1e-5f
#define NB_AGG 3125   // gcn_agg grid
#define NB_COL 512    // input col_stats grid
#define NSPLIT 32     // stats reduction splits

typedef _Float16 f16;
typedef _Float16 half8 __attribute__((ext_vector_type(8)));
typedef _Float16 half4 __attribute__((ext_vector_type(4)));
typedef float floatx4 __attribute__((ext_vector_type(4)));

// ============================ input BN statistics (fp32 x) -> per-block partials ============================
// coalesced layout: part[b*512 + c] (sum), part[b*512 + 256 + c] (sumsq)
__global__ __launch_bounds__(256) void col_stats_kernel(const float* __restrict__ X, int n,
                                                        float* __restrict__ part) {
    int c = threadIdx.x;
    float s = 0.f, q = 0.f;
    for (int i = blockIdx.x; i < n; i += gridDim.x) {
        float v = X[(size_t)i * DIM + c];
        s += v; q += v * v;
    }
    part[(size_t)blockIdx.x * 512 + c] = s;
    part[(size_t)blockIdx.x * 512 + DIM + c] = q;
}

// level-1 reduce: grid (2, NSPLIT); block (bx,by) sums rows [by*chunk, ...) for cols bx*256..+255
// p2[by*512 + col] = partial
__global__ __launch_bounds__(256) void reduce_stats_kernel(const float* __restrict__ part, int nrows,
                                                           float* __restrict__ p2) {
    int col = blockIdx.x * 256 + threadIdx.x;     // 0..511
    int chunk = (nrows + NSPLIT - 1) / NSPLIT;
    int r0 = blockIdx.y * chunk;
    int r1 = min(r0 + chunk, nrows);
    float t = 0.f;
    for (int r = r0; r < r1; r++) t += part[(size_t)r * 512 + col];
    p2[(size_t)blockIdx.y * 512 + col] = t;
}

// level-2 reduce (32 rows) + finalize
__global__ void finalize_stats_kernel(const float* __restrict__ p2, float* __restrict__ mr, float inv_n) {
    int c = threadIdx.x;
    float s = 0.f, q = 0.f;
#pragma unroll
    for (int r = 0; r < NSPLIT; r++) {
        s += p2[(size_t)r * 512 + c];
        q += p2[(size_t)r * 512 + DIM + c];
    }
    float m = s * inv_n;
    float v = q * inv_n - m * m;
    mr[c] = m;
    mr[DIM + c] = rsqrtf(v + EPS_BN);
}

// input BN apply: fp32 x -> fp16 Af
__global__ __launch_bounds__(256) void bn_apply_in_kernel(const float* __restrict__ Xin, f16* __restrict__ Af,
                                                          const float* __restrict__ mr, const float* __restrict__ g,
                                                          const float* __restrict__ b, int n) {
    int c = threadIdx.x;
    float mean = mr[c], rstd = mr[DIM + c], gg = g[c], bb = b[c];
    for (int i = blockIdx.x; i < n; i += gridDim.x) {
        size_t idx = (size_t)i * DIM + c;
        float v = Xin[idx];
        v = (v - mean) * rstd * gg + bb;
        Af[idx] = (f16)v;
    }
}

// layer BN apply: fp16 C (pre-relu) -> relu -> BN -> (+residual Af) -> fp16 Af
__global__ __launch_bounds__(256) void bn_apply_kernel(const f16* __restrict__ Cin, f16* __restrict__ Af,
                                                       const float* __restrict__ mr, const float* __restrict__ g,
                                                       const float* __restrict__ b, int n, int residual) {
    int c = threadIdx.x;
    float mean = mr[c], rstd = mr[DIM + c], gg = g[c], bb = b[c];
    for (int i = blockIdx.x; i < n; i += gridDim.x) {
        size_t idx = (size_t)i * DIM + c;
        float v = (float)Cin[idx];
        v = fmaxf(v, 0.f);
        v = (v - mean) * rstd * gg + bb;
        if (residual) v += (float)Af[idx];
        Af[idx] = (f16)v;
    }
}

// ============================ weight conversion: Wt[m][k] = (f16)W[k][m] ============================
__global__ void convert_wT_kernel(const float* __restrict__ W, f16* __restrict__ Wt, int K, int M) {
    int idx = blockIdx.x * 256 + threadIdx.x;
    if (idx < K * M) {
        int m = idx / K, k = idx % K;
        Wt[idx] = (f16)W[(size_t)k * M + m];
    }
}

// ============================ degree / CSR build ============================
__global__ void count_int_kernel(const int* __restrict__ idx, int n, int* __restrict__ cnt) {
    for (int i = blockIdx.x * blockDim.x + threadIdx.x; i < n; i += gridDim.x * blockDim.x)
        atomicAdd(&cnt[idx[i]], 1);
}

#define SCHUNK 2048
__global__ __launch_bounds__(256) void scan1_kernel(const int* __restrict__ cnt, int n,
                                                    int* __restrict__ outp, int* __restrict__ bsums,
                                                    float* __restrict__ dinv) {
    __shared__ int lds[256];
    int t = threadIdx.x;
    int base = blockIdx.x * SCHUNK + t * 8;
    int v[8]; int s = 0;
#pragma unroll
    for (int j = 0; j < 8; j++) {
        int id = base + j;
        int x = 0;
        if (id < n) { x = cnt[id]; dinv[id] = rsqrtf((float)x + 1.0f); }
        v[j] = s; s += x;
    }
    lds[t] = s; __syncthreads();
    for (int o = 1; o < 256; o <<= 1) {
        int add = (t >= o) ? lds[t - o] : 0;
        __syncthreads();
        lds[t] += add;
        __syncthreads();
    }
    int excl = lds[t] - s;
#pragma unroll
    for (int j = 0; j < 8; j++) { int id = base + j; if (id < n) outp[id] = excl + v[j]; }
    if (t == 255) bsums[blockIdx.x] = lds[255];
}

__global__ void scan2_kernel(int* bsums, int nb) {
    if (threadIdx.x == 0 && blockIdx.x == 0) {
        int r = 0;
        for (int i = 0; i < nb; i++) { int t = bsums[i]; bsums[i] = r; r += t; }
    }
}

__global__ void scan3_kernel(int* __restrict__ outp, const int* __restrict__ bsums, int n, int total) {
    int i = blockIdx.x * blockDim.x + threadIdx.x;
    if (i < n) outp[i] += bsums[i / SCHUNK];
    if (i == 0) outp[n] = total;
}

__global__ void scatter_kernel(const int* __restrict__ src, const int* __restrict__ dst, int ne,
                               const int* __restrict__ rowp, int* __restrict__ fill, int* __restrict__ ss) {
    for (int e = blockIdx.x * blockDim.x + threadIdx.x; e < ne; e += gridDim.x * blockDim.x) {
        int d = dst[e];
        int pos = rowp[d] + atomicAdd(&fill[d], 1);
        ss[pos] = src[e];
    }
}

// ============================ graph ranges (batch sorted -> no atomics) ============================
__global__ void graph_bounds_kernel(const int* __restrict__ batch, int n, int* __restrict__ start) {
    int i = blockIdx.x * blockDim.x + threadIdx.x;
    if (i < n) {
        int b = batch[i];
        if (i == 0 || batch[i - 1] != b) start[b] = i;
    }
}

__global__ void graph_offsets2_kernel(const int* __restrict__ start, int* __restrict__ off, int* __restrict__ cnt) {
    if (threadIdx.x == 0 && blockIdx.x == 0) {
        int nxt = N_NODES;
        for (int g = NG - 1; g >= 0; --g) {
            int s = start[g];
            int o = (s < 0) ? nxt : s;
            off[g] = o;
            cnt[g] = nxt - o;
            nxt = o;
        }
    }
}

// ============================ GCN edge aggregation ============================
// h is PRE-SCALED by dinv (hscaled). out = dinv[row]*(sum_src hscaled + hscaled[row]) + bias
// writes Ch (fp16, pre-relu) AND coalesced per-block BN-stat partials of relu(Ch)
__global__ __launch_bounds__(256) void gcn_agg_kernel(const f16* __restrict__ h, const int* __restrict__ rowp,
                                                      const int* __restrict__ ss, const float* __restrict__ dinv,
                                                      const float* __restrict__ bias, f16* __restrict__ out,
                                                      float* __restrict__ part, int n) {
    int wave = threadIdx.x >> 6;
    int lane = threadIdx.x & 63;
    int c = lane * 4;
    float4 bv = *(const float4*)&bias[c];
    float s0 = 0.f, s1 = 0.f, s2 = 0.f, s3 = 0.f;
    float q0 = 0.f, q1 = 0.f, q2 = 0.f, q3 = 0.f;
    for (int row = blockIdx.x * 4 + wave; row < n; row += gridDim.x * 4) {
        float ax = 0.f, ay = 0.f, az = 0.f, aw = 0.f;
        int e0 = rowp[row], e1 = rowp[row + 1];
        int e = e0;
        for (; e + 3 < e1; e += 4) {
            int i0 = ss[e], i1 = ss[e + 1], i2 = ss[e + 2], i3 = ss[e + 3];
            half4 h0 = *(const half4*)&h[(size_t)i0 * DIM + c];
            half4 h1 = *(const half4*)&h[(size_t)i1 * DIM + c];
            half4 h2 = *(const half4*)&h[(size_t)i2 * DIM + c];
            half4 h3 = *(const half4*)&h[(size_t)i3 * DIM + c];
            ax += (float)h0[0] + (float)h1[0] + (float)h2[0] + (float)h3[0];
            ay += (float)h0[1] + (float)h1[1] + (float)h2[1] + (float)h3[1];
            az += (float)h0[2] + (float)h1[2] + (float)h2[2] + (float)h3[2];
            aw += (float)h0[3] + (float)h1[3] + (float)h2[3] + (float)h3[3];
        }
        for (; e < e1; e++) {
            int si = ss[e];
            half4 hv = *(const half4*)&h[(size_t)si * DIM + c];
            ax += (float)hv[0]; ay += (float)hv[1]; az += (float)hv[2]; aw += (float)hv[3];
        }
        float di = dinv[row];
        half4 hs = *(const half4*)&h[(size_t)row * DIM + c];
        float rx = di * (ax + (float)hs[0]) + bv.x;
        float ry = di * (ay + (float)hs[1]) + bv.y;
        float rz = di * (az + (float)hs[2]) + bv.z;
        float rw = di * (aw + (float)hs[3]) + bv.w;
        half4 o; o[0] = (f16)rx; o[1] = (f16)ry; o[2] = (f16)rz; o[3] = (f16)rw;
        *(half4*)&out[(size_t)row * DIM + c] = o;
        float t;
        t = fmaxf(rx, 0.f); s0 += t; q0 += t * t;
        t = fmaxf(ry, 0.f); s1 += t; q1 += t * t;
        t = fmaxf(rz, 0.f); s2 += t; q2 += t * t;
        t = fmaxf(rw, 0.f); s3 += t; q3 += t * t;
    }
    // cross-wave LDS reduction, then COALESCED per-block partial store: part[b*512 + {c, 256+c}]
    __shared__ float sred[4][64][4];
    __shared__ float qred[4][64][4];
    sred[wave][lane][0] = s0; sred[wave][lane][1] = s1; sred[wave][lane][2] = s2; sred[wave][lane][3] = s3;
    qred[wave][lane][0] = q0; qred[wave][lane][1] = q1; qred[wave][lane][2] = q2; qred[wave][lane][3] = q3;
    __syncthreads();
    if (wave == 0) {
        size_t base = (size_t)blockIdx.x * 512;
        float4 a = make_float4(0.f, 0.f, 0.f, 0.f), qv = make_float4(0.f, 0.f, 0.f, 0.f);
#pragma unroll
        for (int ww = 0; ww < 4; ww++) {
            a.x += sred[ww][lane][0]; a.y += sred[ww][lane][1]; a.z += sred[ww][lane][2]; a.w += sred[ww][lane][3];
            qv.x += qred[ww][lane][0]; qv.y += qred[ww][lane][1]; qv.z += qred[ww][lane][2]; qv.w += qred[ww][lane][3];
        }
        *(float4*)&part[base + c] = a;
        *(float4*)&part[base + DIM + c] = qv;
    }
}

// ============================ fp16 MFMA GEMM: C[n,M] (f16) = scale[row]? * (Af[n,K] @ Wt^T) ============================
#define BM 128
#define BN 128
#define BK 32
#define LDP 40
__global__ __launch_bounds__(256) void gemm_f16_kernel(const f16* __restrict__ Af, const f16* __restrict__ Wt,
                                                       f16* __restrict__ C, const float* __restrict__ scale,
                                                       int n, int K, int M) {
    __shared__ __align__(16) f16 As[BM * LDP];
    __shared__ __align__(16) f16 Bs[BN * LDP];
    int tid = threadIdx.x;
    int wave = tid >> 6, lane = tid & 63;
    int wm = wave >> 1, wn = wave & 1;
    int q = lane >> 4, l16 = lane & 15;
    int bm = blockIdx.x * BM, bn = blockIdx.y * BN;
    floatx4 acc[4][4] = {};
    for (int k0 = 0; k0 < K; k0 += BK) {
#pragma unroll
        for (int rr = 0; rr < 2; rr++) {
            int cidx = tid + rr * 256;
            int row = cidx >> 2, off = (cidx & 3) * 8;
            int arow = bm + row; if (arow >= n) arow = n - 1;
            *(float4*)&As[row * LDP + off] = *(const float4*)&Af[(size_t)arow * K + k0 + off];
            int brow = bn + row;
            *(float4*)&Bs[row * LDP + off] = *(const float4*)&Wt[(size_t)brow * K + k0 + off];
        }
        __syncthreads();
        half8 af[4], bf[4];
#pragma unroll
        for (int i = 0; i < 4; i++) af[i] = *(half8*)&As[(wm * 64 + i * 16 + l16) * LDP + q * 8];
#pragma unroll
        for (int j = 0; j < 4; j++) bf[j] = *(half8*)&Bs[(wn * 64 + j * 16 + l16) * LDP + q * 8];
#pragma unroll
        for (int i = 0; i < 4; i++)
#pragma unroll
            for (int j = 0; j < 4; j++)
                acc[i][j] = __builtin_amdgcn_mfma_f32_16x16x32_f16(af[i], bf[j], acc[i][j], 0, 0, 0);
        __syncthreads();
    }
#pragma unroll
    for (int i = 0; i < 4; i++) {
#pragma unroll
        for (int r = 0; r < 4; r++) {
            int row = bm + wm * 64 + i * 16 + q * 4 + r;
            if (row < n) {
                float sc = scale ? scale[row] : 1.0f;
#pragma unroll
                for (int j = 0; j < 4; j++) {
                    int col = bn + wn * 64 + j * 16 + l16;
                    C[(size_t)row * M + col] = (f16)(acc[i][j][r] * sc);
                }
            }
        }
    }
}

// ============ attention GEMM (M=128) with fused leaky-relu + Wa2 dot -> score ============
__global__ __launch_bounds__(256) void gemm_attn_kernel(const f16* __restrict__ Af, const f16* __restrict__ Wt,
                                                        const float* __restrict__ ba1, const float* __restrict__ Wa2,
                                                        const float* __restrict__ ba2, float* __restrict__ score,
                                                        int n, int K) {
    __shared__ __align__(16) f16 As[BM * LDP];
    __shared__ __align__(16) f16 Bs[128 * LDP];
    __shared__ float scred[128][2];
    int tid = threadIdx.x;
    int wave = tid >> 6, lane = tid & 63;
    int wm = wave >> 1, wn = wave & 1;
    int q = lane >> 4, l16 = lane & 15;
    int bm = blockIdx.x * BM;
    floatx4 acc[4][4] = {};
    for (int k0 = 0; k0 < K; k0 += BK) {
#pragma unroll
        for (int rr = 0; rr < 2; rr++) {
            int cidx = tid + rr * 256;
            int row = cidx >> 2, off = (cidx & 3) * 8;
            int arow = bm + row; if (arow >= n) arow = n - 1;
            *(float4*)&As[row * LDP + off] = *(const float4*)&Af[(size_t)arow * K + k0 + off];
            *(float4*)&Bs[row * LDP + off] = *(const float4*)&Wt[(size_t)row * K + k0 + off];
        }
        __syncthreads();
        half8 af[4], bf[4];
#pragma unroll
        for (int i = 0; i < 4; i++) af[i] = *(half8*)&As[(wm * 64 + i * 16 + l16) * LDP + q * 8];
#pragma unroll
        for (int j = 0; j < 4; j++) bf[j] = *(half8*)&Bs[(wn * 64 + j * 16 + l16) * LDP + q * 8];
#pragma unroll
        for (int i = 0; i < 4; i++)
#pragma unroll
            for (int j = 0; j < 4; j++)
                acc[i][j] = __builtin_amdgcn_mfma_f32_16x16x32_f16(af[i], bf[j], acc[i][j], 0, 0, 0);
        __syncthreads();
    }
    float ba1v[4], wa2v[4];
#pragma unroll
    for (int j = 0; j < 4; j++) {
        int col = wn * 64 + j * 16 + l16;
        ba1v[j] = ba1[col];
        wa2v[j] = Wa2[col];
    }
#pragma unroll
    for (int i = 0; i < 4; i++)
#pragma unroll
        for (int r = 0; r < 4; r++) {
            float p = 0.f;
#pragma unroll
            for (int j = 0; j < 4; j++) {
                float v = acc[i][j][r] + ba1v[j];
                v = (v > 0.f) ? v : 0.01f * v;
                p += v * wa2v[j];
            }
#pragma unroll
            for (int o = 1; o < 16; o <<= 1) p += __shfl_xor(p, o);
            if (l16 == 0) scred[wm * 64 + i * 16 + q * 4 + r][wn] = p;
        }
    __syncthreads();
    if (tid < 128) {
        int grow = bm + tid;
        if (grow < n) score[grow] = scred[tid][0] + scred[tid][1] + ba2[0];
    }
}

// ============================ softmax reductions ============================
__global__ __launch_bounds__(256) void reduce_max_kernel(const float* __restrict__ s, int n, float* __restrict__ part) {
    __shared__ float lds[256];
    float m = -3.0e38f;
    for (int i = blockIdx.x * 256 + threadIdx.x; i < n; i += gridDim.x * 256) m = fmaxf(m, s[i]);
    lds[threadIdx.x] = m; __syncthreads();
    for (int o = 128; o > 0; o >>= 1) {
        if (threadIdx.x < o) lds[threadIdx.x] = fmaxf(lds[threadIdx.x], lds[threadIdx.x + o]);
        __syncthreads();
    }
    if (threadIdx.x == 0) part[blockIdx.x] = lds[0];
}

__global__ __launch_bounds__(256) void reduce_sumexp_kernel(const float* __restrict__ s, int n,
                                                            const float* __restrict__ part_max,
                                                            float* __restrict__ part_sum) {
    __shared__ float lds[256];
    int t = threadIdx.x;
    lds[t] = part_max[t]; __syncthreads();
    for (int o = 128; o > 0; o >>= 1) {
        if (t < o) lds[t] = fmaxf(lds[t], lds[t + o]);
        __syncthreads();
    }
    float mx = lds[0];
    __syncthreads();
    float acc = 0.f;
    for (int i = blockIdx.x * 256 + t; i < n; i += gridDim.x * 256) acc += expf(s[i] - mx);
    lds[t] = acc; __syncthreads();
    for (int o = 128; o > 0; o >>= 1) {
        if (t < o) lds[t] += lds[t + o];
        __syncthreads();
    }
    if (t == 0) part_sum[blockIdx.x] = lds[0];
}

// pooled[g,c] += striped sum of Af[i,c]*exp(score[i]-mx); grid (NG, 8)
__global__ __launch_bounds__(256) void pool_kernel(const f16* __restrict__ Af, const float* __restrict__ score,
                                                   const int* __restrict__ offs, const int* __restrict__ cnts,
                                                   const float* __restrict__ part_max, float* __restrict__ pooled) {
    __shared__ float lds[256];
    int c = threadIdx.x;
    lds[c] = part_max[c]; __syncthreads();
    for (int o = 128; o > 0; o >>= 1) {
        if (c < o) lds[c] = fmaxf(lds[c], lds[c + o]);
        __syncthreads();
    }
    float mx = lds[0];
    int g = blockIdx.x;
    int st = offs[g], cn = cnts[g];
    float acc = 0.f;
    for (int i = (int)blockIdx.y; i < cn; i += 32) {
        int i1 = i + 8, i2 = i + 16, i3 = i + 24;
        float s0 = score[st + i];
        float s1 = (i1 < cn) ? score[st + i1] : -3.0e38f;
        float s2 = (i2 < cn) ? score[st + i2] : -3.0e38f;
        float s3 = (i3 < cn) ? score[st + i3] : -3.0e38f;
        float a0 = (float)Af[(size_t)(st + i) * DIM + c];
        float a1 = (i1 < cn) ? (float)Af[(size_t)(st + i1) * DIM + c] : 0.f;
        float a2 = (i2 < cn) ? (float)Af[(size_t)(st + i2) * DIM + c] : 0.f;
        float a3 = (i3 < cn) ? (float)Af[(size_t)(st + i3) * DIM + c] : 0.f;
        acc += a0 * expf(s0 - mx) + a1 * expf(s1 - mx) + a2 * expf(s2 - mx) + a3 * expf(s3 - mx);
    }
    atomicAdd(&pooled[g * DIM + c], acc);
}

__global__ __launch_bounds__(256) void out_kernel(const float* __restrict__ pooled, const int* __restrict__ cnt,
                                                  const float* __restrict__ part_sum, const float* __restrict__ Wo,
                                                  const float* __restrict__ bo, float* __restrict__ out) {
    __shared__ float l0[256], l1[256];
    int g = blockIdx.x, c = threadIdx.x;
    l0[c] = part_sum[c]; __syncthreads();
    for (int o = 128; o > 0; o >>= 1) {
        if (c < o) l0[c] += l0[c + o];
        __syncthreads();
    }
    float denom = l0[0];
    __syncthreads();
    float scale = 1.f / (denom * fmaxf((float)cnt[g], 1.f));
    float v = pooled[g * DIM + c] * scale;
    l0[c] = v * Wo[c * 2];
    l1[c] = v * Wo[c * 2 + 1];
    __syncthreads();
    for (int o = 128; o > 0; o >>= 1) {
        if (c < o) { l0[c] += l0[c + o]; l1[c] += l1[c + o]; }
        __syncthreads();
    }
    if (c == 0) { out[g * 2] = l0[0] + bo[0]; out[g * 2 + 1] = l1[0] + bo[1]; }
}

// ============================ launch ============================
extern "C" void kernel_launch(void* const* d_in, const int* in_sizes, int n_in,
                              void* d_out, int out_size, void* d_ws, size_t ws_size,
                              hipStream_t stream) {
    const float* x       = (const float*)d_in[0];
    const int*   ei      = (const int*)d_in[1];
    const int*   batch   = (const int*)d_in[2];
    const float* bn_in_g = (const float*)d_in[3];
    const float* bn_in_b = (const float*)d_in[4];
    const float* Ws[3]   = {(const float*)d_in[5],  (const float*)d_in[9],  (const float*)d_in[13]};
    const float* bs[3]   = {(const float*)d_in[6],  (const float*)d_in[10], (const float*)d_in[14]};
    const float* gs[3]   = {(const float*)d_in[7],  (const float*)d_in[11], (const float*)d_in[15]};
    const float* bbs[3]  = {(const float*)d_in[8],  (const float*)d_in[12], (const float*)d_in[16]};
    const float* Wa1 = (const float*)d_in[17];
    const float* ba1 = (const float*)d_in[18];
    const float* Wa2 = (const float*)d_in[19];
    const float* ba2 = (const float*)d_in[20];
    const float* Wo  = (const float*)d_in[21];
    const float* bo  = (const float*)d_in[22];

    char* w = (char*)d_ws;
    size_t off = 0;
    auto alloc = [&](size_t bytes) -> void* {
        void* p = w + off;
        off += (bytes + 255) & ~(size_t)255;
        return p;
    };
    // --- zeroed region (single memset): deg, fill, pooled ---
    int*   deg     = (int*)alloc((size_t)N_NODES * 4);
    int*   fill    = (int*)alloc((size_t)N_NODES * 4);
    float* pooled  = (float*)alloc((size_t)NG * DIM * 4);
    size_t zero_span = off;
    // --- rest (no zeroing needed) ---
    float* stats_part = (float*)alloc((size_t)NB_AGG * 512 * 4);  // per-block partials [b][512]
    float* stats_p2   = (float*)alloc((size_t)NSPLIT * 512 * 4);  // level-1 reduced
    f16*   Afh  = (f16*)alloc((size_t)N_NODES * DIM * 2);   // features fp16
    f16*   Bh   = (f16*)alloc((size_t)N_NODES * DIM * 2);   // hscaled = dinv*(xp @ W) (fp16)
    f16*   Ch   = (f16*)alloc((size_t)N_NODES * DIM * 2);   // aggregated pre-BN (fp16)
    f16*   Wt[3];
    for (int l = 0; l < 3; l++) Wt[l] = (f16*)alloc((size_t)DIM * DIM * 2);
    f16*   Wa1t = (f16*)alloc((size_t)128 * DIM * 2);
    int* sorted_src = (int*)alloc((size_t)N_EDGES * 4);
    float* dinv = (float*)alloc((size_t)N_NODES * 4);
    int* rowp   = (int*)alloc((size_t)(N_NODES + 1) * 4);
    float* score = (float*)alloc((size_t)N_NODES * 4);
    float* mr    = (float*)alloc(512 * 4);
    int* bsums   = (int*)alloc(64 * 4);
    float* part_max = (float*)alloc(256 * 4);
    float* part_sum = (float*)alloc(256 * 4);
    int* gstart  = (int*)alloc(64 * 4);
    int* cnt_g   = (int*)alloc(64 * 4);
    int* off_g   = (int*)alloc(64 * 4);

    const int* src = ei;
    const int* dst = ei + N_EDGES;
    const int NSCAN = (N_NODES + SCHUNK - 1) / SCHUNK;

    hipMemsetAsync(d_ws, 0, zero_span, stream);
    hipMemsetAsync(gstart, 0xff, 64 * 4, stream);

    // ---- degree + CSR (dst-sorted edges); dinv fused into scan1 ----
    count_int_kernel<<<3125, 256, 0, stream>>>(dst, N_EDGES, deg);
    scan1_kernel<<<NSCAN, 256, 0, stream>>>(deg, N_NODES, rowp, bsums, dinv);
    scan2_kernel<<<1, 64, 0, stream>>>(bsums, NSCAN);
    scan3_kernel<<<(N_NODES + 255) / 256, 256, 0, stream>>>(rowp, bsums, N_NODES, N_EDGES);
    scatter_kernel<<<3125, 256, 0, stream>>>(src, dst, N_EDGES, rowp, fill, sorted_src);

    // ---- graph ranges from sorted batch ----
    graph_bounds_kernel<<<(N_NODES + 255) / 256, 256, 0, stream>>>(batch, N_NODES, gstart);
    graph_offsets2_kernel<<<1, 64, 0, stream>>>(gstart, off_g, cnt_g);

    // ---- weight conversion (fp32 -> fp16, transposed) ----
    for (int l = 0; l < 3; l++)
        convert_wT_kernel<<<DIM * DIM / 256, 256, 0, stream>>>(Ws[l], Wt[l], DIM, DIM);
    convert_wT_kernel<<<128 * DIM / 256, 256, 0, stream>>>(Wa1, Wa1t, DIM, 128);

    // ---- input BN (coalesced partials -> 2-level reduce; no atomics) ----
    col_stats_kernel<<<NB_COL, 256, 0, stream>>>(x, N_NODES, stats_part);
    reduce_stats_kernel<<<dim3(2, NSPLIT), 256, 0, stream>>>(stats_part, NB_COL, stats_p2);
    finalize_stats_kernel<<<1, 256, 0, stream>>>(stats_p2, mr, 1.f / N_NODES);
    bn_apply_in_kernel<<<1024, 256, 0, stream>>>(x, Afh, mr, bn_in_g, bn_in_b, N_NODES);

    // ---- GCN layers ----
    dim3 ggrid((N_NODES + BM - 1) / BM, DIM / BN);
    for (int l = 0; l < 3; l++) {
        gemm_f16_kernel<<<ggrid, 256, 0, stream>>>(Afh, Wt[l], Bh, dinv, N_NODES, DIM, DIM);
        gcn_agg_kernel<<<NB_AGG, 256, 0, stream>>>(Bh, rowp, sorted_src, dinv, bs[l], Ch, stats_part, N_NODES);
        reduce_stats_kernel<<<dim3(2, NSPLIT), 256, 0, stream>>>(stats_part, NB_AGG, stats_p2);
        finalize_stats_kernel<<<1, 256, 0, stream>>>(stats_p2, mr, 1.f / N_NODES);
        bn_apply_kernel<<<1024, 256, 0, stream>>>(Ch, Afh, mr, gs[l], bbs[l], N_NODES, (l > 0) ? 1 : 0);
    }

    // ---- attention scores (fused GEMM epilogue) ----
    gemm_attn_kernel<<<(N_NODES + BM - 1) / BM, 256, 0, stream>>>(Afh, Wa1t, ba1, Wa2, ba2, score, N_NODES, DIM);
    reduce_max_kernel<<<256, 256, 0, stream>>>(score, N_NODES, part_max);
    reduce_sumexp_kernel<<<256, 256, 0, stream>>>(score, N_NODES, part_max, part_sum);

    // ---- per-graph pooling ----
    pool_kernel<<<dim3(NG, 8), 256, 0, stream>>>(Afh, score, off_g, cnt_g, part_max, pooled);
    out_kernel<<<NG, 256, 0, stream>>>(pooled, cnt_g, part_sum, Wo, bo, (float*)d_out);
}

// Round 8
// 743.449 us; speedup vs baseline: 2.0113x; 1.0289x over previous
//
#include <hip/hip_runtime.h>

#define N_NODES 50000
#define N_EDGES 800000
#define DIM 256
#define NG 64
#define EPS_BN 1e-5f
#define NB_AGG 3125
#define NB_COL 512
#define NSPLIT 32

typedef _Float16 f16;
typedef _Float16 half8 __attribute__((ext_vector_type(8)));
typedef _Float16 half4 __attribute__((ext_vector_type(4)));
typedef float floatx4 __attribute__((ext_vector_type(4)));

__device__ __forceinline__ int fkey(float f) { int i = __float_as_int(f); return (i >= 0) ? i : (i ^ 0x7fffffff); }
__device__ __forceinline__ float keyf(int k) { return __int_as_float((k >= 0) ? k : (k ^ 0x7fffffff)); }

// ============================ input BN statistics -> coalesced per-block partials ============================
__global__ __launch_bounds__(256) void col_stats_kernel(const float* __restrict__ X, int n,
                                                        float* __restrict__ part) {
    int c = threadIdx.x;
    float s = 0.f, q = 0.f;
    for (int i = blockIdx.x; i < n; i += gridDim.x) {
        float v = X[(size_t)i * DIM + c];
        s += v; q += v * v;
    }
    part[(size_t)blockIdx.x * 512 + c] = s;
    part[(size_t)blockIdx.x * 512 + DIM + c] = q;
}

// ============ merged level-1 reduce + (last block) finalize -> affine A[c]=rstd*g, B[c]=b-mean*A ============
__global__ __launch_bounds__(256) void reduce_finalize_kernel(const float* __restrict__ part, int nrows,
                                                              float* __restrict__ p2, int* __restrict__ counter,
                                                              const float* __restrict__ g, const float* __restrict__ b,
                                                              float* __restrict__ affine, float inv_n) {
    int col = blockIdx.x * 256 + threadIdx.x;   // grid.x = 2 -> 0..511
    int chunk = (nrows + NSPLIT - 1) / NSPLIT;
    int r0 = blockIdx.y * chunk;
    int r1 = min(r0 + chunk, nrows);
    float t = 0.f;
    for (int r = r0; r < r1; r++) t += part[(size_t)r * 512 + col];
    p2[(size_t)blockIdx.y * 512 + col] = t;
    __threadfence();
    __shared__ int lastf;
    if (threadIdx.x == 0) lastf = (atomicAdd(counter, 1) == 2 * NSPLIT - 1) ? 1 : 0;
    __syncthreads();
    if (lastf) {
        __threadfence();
        int c = threadIdx.x;
        float s = 0.f, q = 0.f;
#pragma unroll
        for (int r = 0; r < NSPLIT; r++) {
            s += p2[(size_t)r * 512 + c];
            q += p2[(size_t)r * 512 + DIM + c];
        }
        float m = s * inv_n;
        float v = q * inv_n - m * m;
        float rstd = rsqrtf(v + EPS_BN);
        float A = rstd * g[c];
        affine[c] = A;
        affine[DIM + c] = b[c] - m * A;
    }
}

// ============================ weight conversion, all 4 in one ============================
__global__ void convert_all_kernel(const float* __restrict__ W0, const float* __restrict__ W1,
                                   const float* __restrict__ W2, const float* __restrict__ Wa1,
                                   f16* __restrict__ T0, f16* __restrict__ T1,
                                   f16* __restrict__ T2, f16* __restrict__ T3) {
    int idx = blockIdx.x * 256 + threadIdx.x;    // 0..229375
    if (idx < 196608) {
        int w = idx >> 16, r = idx & 65535;
        const float* W = (w == 0) ? W0 : (w == 1) ? W1 : W2;
        f16* T = (w == 0) ? T0 : (w == 1) ? T1 : T2;
        int m = r >> 8, k = r & 255;
        T[r] = (f16)W[(size_t)k * 256 + m];
    } else {
        int r = idx - 196608;                    // 0..32767
        int m = r >> 8, k = r & 255;
        T3[r] = (f16)Wa1[(size_t)k * 128 + m];
    }
}

// ============================ degree histogram + graph bounds (merged) ============================
__global__ void count_bounds_kernel(const int* __restrict__ dst, int ne, int* __restrict__ cnt,
                                    const int* __restrict__ batch, int n, int* __restrict__ start) {
    int gb = blockIdx.x;
    if (gb < NB_AGG) {
        for (int i = gb * 256 + threadIdx.x; i < ne; i += NB_AGG * 256)
            atomicAdd(&cnt[dst[i]], 1);
    } else {
        int i = (gb - NB_AGG) * 256 + threadIdx.x;
        if (i < n) {
            int b = batch[i];
            if (i == 0 || batch[i - 1] != b) start[b] = i;
        }
    }
}

#define SCHUNK 2048
__global__ __launch_bounds__(256) void scan1_kernel(const int* __restrict__ cnt, int n,
                                                    int* __restrict__ outp, int* __restrict__ bsums,
                                                    float* __restrict__ dinv) {
    __shared__ int lds[256];
    int t = threadIdx.x;
    int base = blockIdx.x * SCHUNK + t * 8;
    int v[8]; int s = 0;
#pragma unroll
    for (int j = 0; j < 8; j++) {
        int id = base + j;
        int x = 0;
        if (id < n) { x = cnt[id]; dinv[id] = rsqrtf((float)x + 1.0f); }
        v[j] = s; s += x;
    }
    lds[t] = s; __syncthreads();
    for (int o = 1; o < 256; o <<= 1) {
        int add = (t >= o) ? lds[t - o] : 0;
        __syncthreads();
        lds[t] += add;
        __syncthreads();
    }
    int excl = lds[t] - s;
#pragma unroll
    for (int j = 0; j < 8; j++) { int id = base + j; if (id < n) outp[id] = excl + v[j]; }
    if (t == 255) bsums[blockIdx.x] = lds[255];
}

// scan3 with inline prefix over raw bsums (25 entries, L2-hot)
__global__ void scan3_kernel(int* __restrict__ outp, const int* __restrict__ bsums, int n, int total) {
    int i = blockIdx.x * blockDim.x + threadIdx.x;
    if (i < n) {
        int k = i / SCHUNK;
        int pref = 0;
        for (int j = 0; j < k; j++) pref += bsums[j];
        outp[i] += pref;
    }
    if (i == 0) outp[n] = total;
}

__global__ void scatter_kernel(const int* __restrict__ src, const int* __restrict__ dst, int ne,
                               const int* __restrict__ rowp, int* __restrict__ fill, int* __restrict__ ss) {
    for (int e = blockIdx.x * blockDim.x + threadIdx.x; e < ne; e += gridDim.x * blockDim.x) {
        int d = dst[e];
        int pos = rowp[d] + atomicAdd(&fill[d], 1);
        ss[pos] = src[e];
    }
}

// graph offsets + init of attention max-key scalar
__global__ void graph_offsets2_kernel(const int* __restrict__ start, int* __restrict__ off, int* __restrict__ cnt,
                                      int* __restrict__ maxkey) {
    if (threadIdx.x == 0 && blockIdx.x == 0) {
        int nxt = N_NODES;
        for (int g = NG - 1; g >= 0; --g) {
            int s = start[g];
            int o = (s < 0) ? nxt : s;
            off[g] = o;
            cnt[g] = nxt - o;
            nxt = o;
        }
        maxkey[0] = 0x80000000;   // -inf key
    }
}

// ============================ GCN edge aggregation (scalar-indexed, unroll 8) ============================
__global__ __launch_bounds__(256) void gcn_agg_kernel(const f16* __restrict__ h, const int* __restrict__ rowp,
                                                      const int* __restrict__ ss, const float* __restrict__ dinv,
                                                      const float* __restrict__ bias, f16* __restrict__ out,
                                                      float* __restrict__ part, int n) {
    int wave = threadIdx.x >> 6;
    int lane = threadIdx.x & 63;
    int c = lane * 4;
    float4 bv = *(const float4*)&bias[c];
    float s0a = 0.f, s1a = 0.f, s2a = 0.f, s3a = 0.f;
    float q0a = 0.f, q1a = 0.f, q2a = 0.f, q3a = 0.f;
    for (int row = blockIdx.x * 4 + wave; row < n; row += gridDim.x * 4) {
        float ax = 0.f, ay = 0.f, az = 0.f, aw = 0.f;
        int e0 = rowp[row], e1 = rowp[row + 1];
        int e = e0;
        for (; e + 8 <= e1; e += 8) {
            int i0 = __builtin_amdgcn_readfirstlane(ss[e + 0]);
            int i1 = __builtin_amdgcn_readfirstlane(ss[e + 1]);
            int i2 = __builtin_amdgcn_readfirstlane(ss[e + 2]);
            int i3 = __builtin_amdgcn_readfirstlane(ss[e + 3]);
            int i4 = __builtin_amdgcn_readfirstlane(ss[e + 4]);
            int i5 = __builtin_amdgcn_readfirstlane(ss[e + 5]);
            int i6 = __builtin_amdgcn_readfirstlane(ss[e + 6]);
            int i7 = __builtin_amdgcn_readfirstlane(ss[e + 7]);
            half4 v0 = *(const half4*)&h[((size_t)i0 << 8) + c];
            half4 v1 = *(const half4*)&h[((size_t)i1 << 8) + c];
            half4 v2 = *(const half4*)&h[((size_t)i2 << 8) + c];
            half4 v3 = *(const half4*)&h[((size_t)i3 << 8) + c];
            half4 v4 = *(const half4*)&h[((size_t)i4 << 8) + c];
            half4 v5 = *(const half4*)&h[((size_t)i5 << 8) + c];
            half4 v6 = *(const half4*)&h[((size_t)i6 << 8) + c];
            half4 v7 = *(const half4*)&h[((size_t)i7 << 8) + c];
            ax += ((float)v0[0] + (float)v1[0]) + ((float)v2[0] + (float)v3[0]) +
                  ((float)v4[0] + (float)v5[0]) + ((float)v6[0] + (float)v7[0]);
            ay += ((float)v0[1] + (float)v1[1]) + ((float)v2[1] + (float)v3[1]) +
                  ((float)v4[1] + (float)v5[1]) + ((float)v6[1] + (float)v7[1]);
            az += ((float)v0[2] + (float)v1[2]) + ((float)v2[2] + (float)v3[2]) +
                  ((float)v4[2] + (float)v5[2]) + ((float)v6[2] + (float)v7[2]);
            aw += ((float)v0[3] + (float)v1[3]) + ((float)v2[3] + (float)v3[3]) +
                  ((float)v4[3] + (float)v5[3]) + ((float)v6[3] + (float)v7[3]);
        }
        for (; e < e1; e++) {
            int si = __builtin_amdgcn_readfirstlane(ss[e]);
            half4 hv = *(const half4*)&h[((size_t)si << 8) + c];
            ax += (float)hv[0]; ay += (float)hv[1]; az += (float)hv[2]; aw += (float)hv[3];
        }
        float di = dinv[row];
        half4 hs = *(const half4*)&h[((size_t)row << 8) + c];
        float rx = di * (ax + (float)hs[0]) + bv.x;
        float ry = di * (ay + (float)hs[1]) + bv.y;
        float rz = di * (az + (float)hs[2]) + bv.z;
        float rw = di * (aw + (float)hs[3]) + bv.w;
        half4 o; o[0] = (f16)rx; o[1] = (f16)ry; o[2] = (f16)rz; o[3] = (f16)rw;
        *(half4*)&out[((size_t)row << 8) + c] = o;
        float t;
        t = fmaxf(rx, 0.f); s0a += t; q0a += t * t;
        t = fmaxf(ry, 0.f); s1a += t; q1a += t * t;
        t = fmaxf(rz, 0.f); s2a += t; q2a += t * t;
        t = fmaxf(rw, 0.f); s3a += t; q3a += t * t;
    }
    __shared__ float sred[4][64][4];
    __shared__ float qred[4][64][4];
    sred[wave][lane][0] = s0a; sred[wave][lane][1] = s1a; sred[wave][lane][2] = s2a; sred[wave][lane][3] = s3a;
    qred[wave][lane][0] = q0a; qred[wave][lane][1] = q1a; qred[wave][lane][2] = q2a; qred[wave][lane][3] = q3a;
    __syncthreads();
    if (wave == 0) {
        size_t base = (size_t)blockIdx.x * 512;
        float4 a = make_float4(0.f, 0.f, 0.f, 0.f), qv = make_float4(0.f, 0.f, 0.f, 0.f);
#pragma unroll
        for (int ww = 0; ww < 4; ww++) {
            a.x += sred[ww][lane][0]; a.y += sred[ww][lane][1]; a.z += sred[ww][lane][2]; a.w += sred[ww][lane][3];
            qv.x += qred[ww][lane][0]; qv.y += qred[ww][lane][1]; qv.z += qred[ww][lane][2]; qv.w += qred[ww][lane][3];
        }
        *(float4*)&part[base + c] = a;
        *(float4*)&part[base + DIM + c] = qv;
    }
}

// ============================ fused BN + MFMA GEMM ============================
// A-source: Xf32 (input mode, affine only) OR Ch (relu+affine, optional residual from Aold).
// Staged fp16 features optionally written to Afout (blockIdx.y==0 only). Epilogue scales rows by dinv.
#define BM 128
#define BN 128
#define BK 32
#define LDP 40
__global__ __launch_bounds__(256) void gemm_fused_kernel(const float* __restrict__ Xf32, const f16* __restrict__ Ch,
                                                         const f16* __restrict__ Aold, f16* __restrict__ Afout,
                                                         const float* __restrict__ affine,
                                                         const f16* __restrict__ Wt, f16* __restrict__ Cout,
                                                         const float* __restrict__ scale, int n, int K, int M) {
    __shared__ __align__(16) f16 As[BM * LDP];
    __shared__ __align__(16) f16 Bs[BN * LDP];
    __shared__ float sA[256], sB[256];
    int tid = threadIdx.x;
    if (tid < 256) { sA[tid] = affine[tid]; sB[tid] = affine[256 + tid]; }
    int wave = tid >> 6, lane = tid & 63;
    int wm = wave >> 1, wn = wave & 1;
    int q = lane >> 4, l16 = lane & 15;
    int bm = blockIdx.x * BM, bn = blockIdx.y * BN;
    int kc = (tid & 3) * 8;                  // same for both rr iterations
    int writer = (Afout != nullptr) && (blockIdx.y == 0);
    floatx4 acc[4][4] = {};
    __syncthreads();
    for (int k0 = 0; k0 < K; k0 += BK) {
        float a8[8], b8[8];
#pragma unroll
        for (int j = 0; j < 8; j++) { a8[j] = sA[k0 + kc + j]; b8[j] = sB[k0 + kc + j]; }
#pragma unroll
        for (int rr = 0; rr < 2; rr++) {
            int cidx = tid + rr * 256;
            int row = cidx >> 2;
            int arow = bm + row; if (arow >= n) arow = n - 1;
            float v[8];
            if (Xf32) {
                float4 x0 = *(const float4*)&Xf32[(size_t)arow * K + k0 + kc];
                float4 x1 = *(const float4*)&Xf32[(size_t)arow * K + k0 + kc + 4];
                v[0] = x0.x; v[1] = x0.y; v[2] = x0.z; v[3] = x0.w;
                v[4] = x1.x; v[5] = x1.y; v[6] = x1.z; v[7] = x1.w;
            } else {
                half8 ch = *(const half8*)&Ch[(size_t)arow * K + k0 + kc];
#pragma unroll
                for (int j = 0; j < 8; j++) v[j] = fmaxf((float)ch[j], 0.f);
            }
            half8 af;
            if (Aold) {
                half8 ao = *(const half8*)&Aold[(size_t)arow * K + k0 + kc];
#pragma unroll
                for (int j = 0; j < 8; j++) af[j] = (f16)(v[j] * a8[j] + b8[j] + (float)ao[j]);
            } else {
#pragma unroll
                for (int j = 0; j < 8; j++) af[j] = (f16)(v[j] * a8[j] + b8[j]);
            }
            *(float4*)&As[row * LDP + kc] = *(float4*)&af;
            if (writer && bm + row < n) *(half8*)&Afout[(size_t)arow * K + k0 + kc] = af;
            int brow = bn + row;
            *(float4*)&Bs[row * LDP + kc] = *(const float4*)&Wt[(size_t)brow * K + k0 + kc];
        }
        __syncthreads();
        half8 afr[4], bfr[4];
#pragma unroll
        for (int i = 0; i < 4; i++) afr[i] = *(half8*)&As[(wm * 64 + i * 16 + l16) * LDP + q * 8];
#pragma unroll
        for (int j = 0; j < 4; j++) bfr[j] = *(half8*)&Bs[(wn * 64 + j * 16 + l16) * LDP + q * 8];
#pragma unroll
        for (int i = 0; i < 4; i++)
#pragma unroll
            for (int j = 0; j < 4; j++)
                acc[i][j] = __builtin_amdgcn_mfma_f32_16x16x32_f16(afr[i], bfr[j], acc[i][j], 0, 0, 0);
        __syncthreads();
    }
#pragma unroll
    for (int i = 0; i < 4; i++) {
#pragma unroll
        for (int r = 0; r < 4; r++) {
            int row = bm + wm * 64 + i * 16 + q * 4 + r;
            if (row < n) {
                float sc = scale[row];
#pragma unroll
                for (int j = 0; j < 4; j++) {
                    int col = bn + wn * 64 + j * 16 + l16;
                    Cout[(size_t)row * M + col] = (f16)(acc[i][j][r] * sc);
                }
            }
        }
    }
}

// ============ attention GEMM: fused BN staging + leaky+Wa2 epilogue + atomicMax, writes Af3 ============
__global__ __launch_bounds__(256) void gemm_attn_kernel(const f16* __restrict__ Ch, const f16* __restrict__ Aold,
                                                        f16* __restrict__ Afout, const float* __restrict__ affine,
                                                        const f16* __restrict__ Wt,
                                                        const float* __restrict__ ba1, const float* __restrict__ Wa2,
                                                        const float* __restrict__ ba2, float* __restrict__ score,
                                                        int* __restrict__ maxkey, int n, int K) {
    __shared__ __align__(16) f16 As[BM * LDP];
    __shared__ __align__(16) f16 Bs[128 * LDP];
    __shared__ float sA[256], sB[256];
    __shared__ float scred[128][2];
    int tid = threadIdx.x;
    if (tid < 256) { sA[tid] = affine[tid]; sB[tid] = affine[256 + tid]; }
    int wave = tid >> 6, lane = tid & 63;
    int wm = wave >> 1, wn = wave & 1;
    int q = lane >> 4, l16 = lane & 15;
    int bm = blockIdx.x * BM;
    int kc = (tid & 3) * 8;
    floatx4 acc[4][4] = {};
    __syncthreads();
    for (int k0 = 0; k0 < K; k0 += BK) {
        float a8[8], b8[8];
#pragma unroll
        for (int j = 0; j < 8; j++) { a8[j] = sA[k0 + kc + j]; b8[j] = sB[k0 + kc + j]; }
#pragma unroll
        for (int rr = 0; rr < 2; rr++) {
            int cidx = tid + rr * 256;
            int row = cidx >> 2;
            int arow = bm + row; if (arow >= n) arow = n - 1;
            half8 ch = *(const half8*)&Ch[(size_t)arow * K + k0 + kc];
            half8 ao = *(const half8*)&Aold[(size_t)arow * K + k0 + kc];
            half8 af;
#pragma unroll
            for (int j = 0; j < 8; j++)
                af[j] = (f16)(fmaxf((float)ch[j], 0.f) * a8[j] + b8[j] + (float)ao[j]);
            *(float4*)&As[row * LDP + kc] = *(float4*)&af;
            if (bm + row < n) *(half8*)&Afout[(size_t)arow * K + k0 + kc] = af;
            *(float4*)&Bs[row * LDP + kc] = *(const float4*)&Wt[(size_t)row * K + k0 + kc];
        }
        __syncthreads();
        half8 afr[4], bfr[4];
#pragma unroll
        for (int i = 0; i < 4; i++) afr[i] = *(half8*)&As[(wm * 64 + i * 16 + l16) * LDP + q * 8];
#pragma unroll
        for (int j = 0; j < 4; j++) bfr[j] = *(half8*)&Bs[(wn * 64 + j * 16 + l16) * LDP + q * 8];
#pragma unroll
        for (int i = 0; i < 4; i++)
#pragma unroll
            for (int j = 0; j < 4; j++)
                acc[i][j] = __builtin_amdgcn_mfma_f32_16x16x32_f16(afr[i], bfr[j], acc[i][j], 0, 0, 0);
        __syncthreads();
    }
    float ba1v[4], wa2v[4];
#pragma unroll
    for (int j = 0; j < 4; j++) {
        int col = wn * 64 + j * 16 + l16;
        ba1v[j] = ba1[col];
        wa2v[j] = Wa2[col];
    }
#pragma unroll
    for (int i = 0; i < 4; i++)
#pragma unroll
        for (int r = 0; r < 4; r++) {
            float p = 0.f;
#pragma unroll
            for (int j = 0; j < 4; j++) {
                float v = acc[i][j][r] + ba1v[j];
                v = (v > 0.f) ? v : 0.01f * v;
                p += v * wa2v[j];
            }
#pragma unroll
            for (int o = 1; o < 16; o <<= 1) p += __shfl_xor(p, o);
            if (l16 == 0) scred[wm * 64 + i * 16 + q * 4 + r][wn] = p;
        }
    __syncthreads();
    __shared__ float mred[128];
    if (tid < 128) {
        int grow = bm + tid;
        float sc = scred[tid][0] + scred[tid][1] + ba2[0];
        if (grow < n) score[grow] = sc; else sc = -3.0e38f;
        mred[tid] = sc;
    }
    __syncthreads();
    for (int o = 64; o > 0; o >>= 1) {
        if (tid < o && tid + o < 128) mred[tid] = fmaxf(mred[tid], mred[tid + o]);
        __syncthreads();
    }
    if (tid == 0) atomicMax(maxkey, fkey(mred[0]));
}

// pooled[g,c] += striped sum of Af[i,c]*exp(score[i]-mx); also accumulates global sum-exp. grid (NG, 8)
__global__ __launch_bounds__(256) void pool_kernel(const f16* __restrict__ Af, const float* __restrict__ score,
                                                   const int* __restrict__ offs, const int* __restrict__ cnts,
                                                   const int* __restrict__ maxkey, float* __restrict__ expsum,
                                                   float* __restrict__ pooled) {
    float mx = keyf(maxkey[0]);
    int c = threadIdx.x;
    int g = blockIdx.x;
    int st = offs[g], cn = cnts[g];
    float acc = 0.f, esum = 0.f;
    for (int i = (int)blockIdx.y; i < cn; i += 32) {
        int i1 = i + 8, i2 = i + 16, i3 = i + 24;
        float s0 = score[st + i];
        float s1 = (i1 < cn) ? score[st + i1] : -3.0e38f;
        float s2 = (i2 < cn) ? score[st + i2] : -3.0e38f;
        float s3 = (i3 < cn) ? score[st + i3] : -3.0e38f;
        float e0 = expf(s0 - mx), e1 = expf(s1 - mx), e2 = expf(s2 - mx), e3 = expf(s3 - mx);
        float a0 = (float)Af[(size_t)(st + i) * DIM + c];
        float a1 = (i1 < cn) ? (float)Af[(size_t)(st + i1) * DIM + c] : 0.f;
        float a2 = (i2 < cn) ? (float)Af[(size_t)(st + i2) * DIM + c] : 0.f;
        float a3 = (i3 < cn) ? (float)Af[(size_t)(st + i3) * DIM + c] : 0.f;
        acc += a0 * e0 + a1 * e1 + a2 * e2 + a3 * e3;
        esum += (e0 + e1) + (e2 + e3);
    }
    atomicAdd(&pooled[g * DIM + c], acc);
    if (c == 0) atomicAdd(expsum, esum);
}

__global__ __launch_bounds__(256) void out_kernel(const float* __restrict__ pooled, const int* __restrict__ cnt,
                                                  const float* __restrict__ expsum, const float* __restrict__ Wo,
                                                  const float* __restrict__ bo, float* __restrict__ out) {
    __shared__ float l0[256], l1[256];
    int g = blockIdx.x, c = threadIdx.x;
    float scale = 1.f / (expsum[0] * fmaxf((float)cnt[g], 1.f));
    float v = pooled[g * DIM + c] * scale;
    l0[c] = v * Wo[c * 2];
    l1[c] = v * Wo[c * 2 + 1];
    __syncthreads();
    for (int o = 128; o > 0; o >>= 1) {
        if (c < o) { l0[c] += l0[c + o]; l1[c] += l1[c + o]; }
        __syncthreads();
    }
    if (c == 0) { out[g * 2] = l0[0] + bo[0]; out[g * 2 + 1] = l1[0] + bo[1]; }
}

// ============================ launch ============================
extern "C" void kernel_launch(void* const* d_in, const int* in_sizes, int n_in,
                              void* d_out, int out_size, void* d_ws, size_t ws_size,
                              hipStream_t stream) {
    const float* x       = (const float*)d_in[0];
    const int*   ei      = (const int*)d_in[1];
    const int*   batch   = (const int*)d_in[2];
    const float* bn_in_g = (const float*)d_in[3];
    const float* bn_in_b = (const float*)d_in[4];
    const float* Ws[3]   = {(const float*)d_in[5],  (const float*)d_in[9],  (const float*)d_in[13]};
    const float* bs[3]   = {(const float*)d_in[6],  (const float*)d_in[10], (const float*)d_in[14]};
    const float* gs[3]   = {(const float*)d_in[7],  (const float*)d_in[11], (const float*)d_in[15]};
    const float* bbs[3]  = {(const float*)d_in[8],  (const float*)d_in[12], (const float*)d_in[16]};
    const float* Wa1 = (const float*)d_in[17];
    const float* ba1 = (const float*)d_in[18];
    const float* Wa2 = (const float*)d_in[19];
    const float* ba2 = (const float*)d_in[20];
    const float* Wo  = (const float*)d_in[21];
    const float* bo  = (const float*)d_in[22];

    char* w = (char*)d_ws;
    size_t off = 0;
    auto alloc = [&](size_t bytes) -> void* {
        void* p = w + off;
        off += (bytes + 255) & ~(size_t)255;
        return p;
    };
    // --- zeroed region (single memset): deg, fill, pooled, counters, expsum ---
    int*   deg     = (int*)alloc((size_t)N_NODES * 4);
    int*   fill    = (int*)alloc((size_t)N_NODES * 4);
    float* pooled  = (float*)alloc((size_t)NG * DIM * 4);
    int*   counters = (int*)alloc(4 * 4);
    float* expsum  = (float*)alloc(4);
    size_t zero_span = off;
    // --- rest ---
    float* stats_part = (float*)alloc((size_t)NB_AGG * 512 * 4);
    float* stats_p2   = (float*)alloc((size_t)NSPLIT * 512 * 4);
    float* affine  = (float*)alloc(512 * 4);
    f16*   AfA  = (f16*)alloc((size_t)N_NODES * DIM * 2);
    f16*   AfB  = (f16*)alloc((size_t)N_NODES * DIM * 2);
    f16*   Bh   = (f16*)alloc((size_t)N_NODES * DIM * 2);   // hscaled
    f16*   Chb  = (f16*)alloc((size_t)N_NODES * DIM * 2);   // aggregated pre-BN
    f16*   Wt[3];
    for (int l = 0; l < 3; l++) Wt[l] = (f16*)alloc((size_t)DIM * DIM * 2);
    f16*   Wa1t = (f16*)alloc((size_t)128 * DIM * 2);
    int* sorted_src = (int*)alloc((size_t)N_EDGES * 4);
    float* dinv = (float*)alloc((size_t)N_NODES * 4);
    int* rowp   = (int*)alloc((size_t)(N_NODES + 1) * 4);
    float* score = (float*)alloc((size_t)N_NODES * 4);
    int* bsums   = (int*)alloc(64 * 4);
    int* maxkey  = (int*)alloc(16);
    int* gstart  = (int*)alloc(64 * 4);
    int* cnt_g   = (int*)alloc(64 * 4);
    int* off_g   = (int*)alloc(64 * 4);

    const int* src = ei;
    const int* dst = ei + N_EDGES;
    const int NSCAN = (N_NODES + SCHUNK - 1) / SCHUNK;
    const float inv_n = 1.f / N_NODES;

    hipMemsetAsync(d_ws, 0, zero_span, stream);
    hipMemsetAsync(gstart, 0xff, 64 * 4, stream);

    // ---- CSR build + graph bounds ----
    count_bounds_kernel<<<NB_AGG + 196, 256, 0, stream>>>(dst, N_EDGES, deg, batch, N_NODES, gstart);
    scan1_kernel<<<NSCAN, 256, 0, stream>>>(deg, N_NODES, rowp, bsums, dinv);
    scan3_kernel<<<(N_NODES + 255) / 256, 256, 0, stream>>>(rowp, bsums, N_NODES, N_EDGES);
    scatter_kernel<<<NB_AGG, 256, 0, stream>>>(src, dst, N_EDGES, rowp, fill, sorted_src);
    graph_offsets2_kernel<<<1, 64, 0, stream>>>(gstart, off_g, cnt_g, maxkey);

    // ---- weights ----
    convert_all_kernel<<<896, 256, 0, stream>>>(Ws[0], Ws[1], Ws[2], Wa1, Wt[0], Wt[1], Wt[2], Wa1t);

    // ---- input BN stats -> affine ----
    col_stats_kernel<<<NB_COL, 256, 0, stream>>>(x, N_NODES, stats_part);
    reduce_finalize_kernel<<<dim3(2, NSPLIT), 256, 0, stream>>>(stats_part, NB_COL, stats_p2, counters + 0,
                                                                bn_in_g, bn_in_b, affine, inv_n);

    // ---- GCN layers (BN fused into GEMM staging) ----
    dim3 ggrid((N_NODES + BM - 1) / BM, DIM / BN);
    // layer 0: A = BN_in(x); no residual, no Af write
    gemm_fused_kernel<<<ggrid, 256, 0, stream>>>(x, nullptr, nullptr, nullptr, affine, Wt[0], Bh, dinv, N_NODES, DIM, DIM);
    gcn_agg_kernel<<<NB_AGG, 256, 0, stream>>>(Bh, rowp, sorted_src, dinv, bs[0], Chb, stats_part, N_NODES);
    reduce_finalize_kernel<<<dim3(2, NSPLIT), 256, 0, stream>>>(stats_part, NB_AGG, stats_p2, counters + 1,
                                                                gs[0], bbs[0], affine, inv_n);
    // layer 1: A = BN0(relu(Ch)); write AfA
    gemm_fused_kernel<<<ggrid, 256, 0, stream>>>(nullptr, Chb, nullptr, AfA, affine, Wt[1], Bh, dinv, N_NODES, DIM, DIM);
    gcn_agg_kernel<<<NB_AGG, 256, 0, stream>>>(Bh, rowp, sorted_src, dinv, bs[1], Chb, stats_part, N_NODES);
    reduce_finalize_kernel<<<dim3(2, NSPLIT), 256, 0, stream>>>(stats_part, NB_AGG, stats_p2, counters + 2,
                                                                gs[1], bbs[1], affine, inv_n);
    // layer 2: A = BN1(relu(Ch)) + AfA; write AfB
    gemm_fused_kernel<<<ggrid, 256, 0, stream>>>(nullptr, Chb, AfA, AfB, affine, Wt[2], Bh, dinv, N_NODES, DIM, DIM);
    gcn_agg_kernel<<<NB_AGG, 256, 0, stream>>>(Bh, rowp, sorted_src, dinv, bs[2], Chb, stats_part, N_NODES);
    reduce_finalize_kernel<<<dim3(2, NSPLIT), 256, 0, stream>>>(stats_part, NB_AGG, stats_p2, counters + 3,
                                                                gs[2], bbs[2], affine, inv_n);

    // ---- attention: A = BN2(relu(Ch)) + AfB -> AfA; fused score + global max ----
    gemm_attn_kernel<<<(N_NODES + BM - 1) / BM, 256, 0, stream>>>(Chb, AfB, AfA, affine, Wa1t,
                                                                  ba1, Wa2, ba2, score, maxkey, N_NODES, DIM);

    // ---- pooling + output ----
    pool_kernel<<<dim3(NG, 8), 256, 0, stream>>>(AfA, score, off_g, cnt_g, maxkey, expsum, pooled);
    out_kernel<<<NG, 256, 0, stream>>>(pooled, cnt_g, expsum, Wo, bo, (float*)d_out);
}